// Round 1
// baseline (377.201 us; speedup 1.0000x reference)
//
#include <hip/hip_runtime.h>
#include <hip/hip_bf16.h>
#include <math.h>

#define B_   2
#define L_   2048
#define E_   1024
#define H_   16
#define DH   64
#define DFF  4096
#define M_   4096
#define APAD 72
#define SCALE_Q 0.18033688011112042f   // log2(e)/8, folded into Wq/bq

typedef __attribute__((ext_vector_type(8))) short short8;
typedef __attribute__((ext_vector_type(4))) float f32x4;
typedef __bf16 bf16x8 __attribute__((ext_vector_type(8)));

__device__ __forceinline__ float bf2f(unsigned short u) {
    return __uint_as_float(((unsigned)u) << 16);
}
__device__ __forceinline__ unsigned short f2bf(float f) {
    unsigned u = __float_as_uint(f);
    return (unsigned short)((u + 0x7fff + ((u >> 16) & 1)) >> 16);
}
__device__ __forceinline__ unsigned pk_trunc(float lo, float hi) {
    return (__float_as_uint(lo) >> 16) | (__float_as_uint(hi) & 0xffff0000u);
}

// Async global->LDS, 16 bytes per lane. LDS dest is wave-uniform base +
// lane*16B (hardware-defined); global src is per-lane.
__device__ __forceinline__ void gld16(const unsigned short* g, unsigned short* l) {
    __builtin_amdgcn_global_load_lds(
        (const __attribute__((address_space(1))) void*)g,
        (__attribute__((address_space(3))) void*)l, 16, 0, 0);
}

// ---------------------------------------------------------------------------
// Fused preprocessing (task-decoded 1-D grid), unchanged.
// ---------------------------------------------------------------------------
__global__ __launch_bounds__(256) void prep(const float* __restrict__ x,
                                            const float* __restrict__ Wq,
                                            const float* __restrict__ Wk,
                                            const float* __restrict__ Wv,
                                            const float* __restrict__ bq,
                                            const float* __restrict__ bk,
                                            const float* __restrict__ bv,
                                            const float* __restrict__ Wo,
                                            const float* __restrict__ W1,
                                            const float* __restrict__ W2,
                                            unsigned short* __restrict__ xb,
                                            unsigned short* __restrict__ Wqkvt,
                                            unsigned short* __restrict__ Wot,
                                            unsigned short* __restrict__ W1t,
                                            unsigned short* __restrict__ W2t,
                                            float* __restrict__ bqkv) {
    __shared__ float tile[32][33];
    int bid = blockIdx.x;
    const int t = threadIdx.x;

    if (bid < 4096) {                      // x -> bf16
        int i = (bid * 256 + t) * 4;
        float4 v = *(const float4*)&x[i];
        ushort4 pk = { f2bf(v.x), f2bf(v.y), f2bf(v.z), f2bf(v.w) };
        *(ushort4*)&xb[i] = pk;
        return;
    }
    bid -= 4096;

    const float* in; unsigned short* outp; int R, C, r0, c0; float sc = 1.f;
    if (bid < 3072) {                      // Wqkv: per-head [E][DH] -> [DH][E]
        int xq = bid & 1, yq = (bid >> 1) & 31, wh = bid >> 6;
        int which = wh >> 4, h = wh & 15;
        in   = (which == 0 ? Wq : which == 1 ? Wk : Wv) + (size_t)h * E_ * DH;
        outp = Wqkvt + ((size_t)which * 1024 + h * 64) * 1024;
        R = E_; C = DH; r0 = yq * 32; c0 = xq * 32;
        if (which == 0) sc = SCALE_Q;
    } else if (bid < 4096) {               // Wo [E][E]
        bid -= 3072;
        in = Wo; outp = Wot; R = E_; C = E_;
        c0 = (bid & 31) * 32; r0 = (bid >> 5) * 32;
    } else if (bid < 8192) {               // W1 [E][DFF]
        bid -= 4096;
        in = W1; outp = W1t; R = E_; C = DFF;
        c0 = (bid & 127) * 32; r0 = (bid >> 7) * 32;
    } else if (bid < 12288) {              // W2 [DFF][E]
        bid -= 8192;
        in = W2; outp = W2t; R = DFF; C = E_;
        c0 = (bid & 31) * 32; r0 = (bid >> 5) * 32;
    } else {                               // bqkv
        bid -= 12288;
        int n = bid * 256 + t;
        bqkv[n] = n < 1024 ? bq[n] * SCALE_Q : n < 2048 ? bk[n - 1024] : bv[n - 2048];
        return;
    }

    const int tx = t & 31, tq = t >> 5;
#pragma unroll
    for (int s2 = 0; s2 < 4; s2++)
        tile[tq * 4 + s2][tx] = in[(size_t)(r0 + tq * 4 + s2) * C + c0 + tx] * sc;
    __syncthreads();
#pragma unroll
    for (int s2 = 0; s2 < 4; s2++)
        outp[(size_t)(c0 + tq * 4 + s2) * R + r0 + tx] = f2bf(tile[tx][tq * 4 + s2]);
}

// ---------------------------------------------------------------------------
// V pre-transpose with pi-permuted columns (unchanged).
// ---------------------------------------------------------------------------
__global__ __launch_bounds__(256) void v_transpose_perm(const unsigned short* __restrict__ qkv,
                                                        unsigned short* __restrict__ vtg) {
    __shared__ unsigned short tile[64 * APAD];
    const int t  = threadIdx.x;
    const int kt = blockIdx.x, hh = blockIdx.y, b = blockIdx.z;
    const int rr0 = t >> 3, o8 = (t & 7) * 8, rr1 = rr0 + 32;
    const size_t gbase = ((size_t)b * L_ + kt * 64) * 3072 + 2048 + hh * 64;
    *(short8*)&tile[rr0 * APAD + o8] = *(const short8*)&qkv[gbase + (size_t)rr0 * 3072 + o8];
    *(short8*)&tile[rr1 * APAD + o8] = *(const short8*)&qkv[gbase + (size_t)rr1 * 3072 + o8];
    __syncthreads();
    const size_t obase = ((size_t)(b * H_ + hh) * 64) * (size_t)L_ + kt * 64;
    const int a = t & 15, d0 = (t >> 4) * 4;
#pragma unroll
    for (int s2 = 0; s2 < 4; s2++) {
        int d = d0 + s2;
        ushort4 pk = { tile[(a +  0) * APAD + d], tile[(a + 16) * APAD + d],
                       tile[(a + 32) * APAD + d], tile[(a + 48) * APAD + d] };
        *(ushort4*)&vtg[obase + (size_t)d * L_ + 4 * a] = pk;
    }
}

// ---------------------------------------------------------------------------
// bf16 MFMA GEMM, B^T layout, 128x128, global_load_lds (width-16) staging,
// double-buffered LDS, one barrier/iter (m97 structure). XCD m-band swizzle.
// Grid = Nt*32 (1-D).
// LDS layout is lane-linear: element offset t*8 == byte t*16, so the wave-
// uniform-base + lane*16B write pattern of global_load_lds lands exactly on
// the [row][32k] layout the ds_read_b128 fragment reads expect.
// ---------------------------------------------------------------------------
template <int RELU, int OUT_BF16>
__global__ __launch_bounds__(256) void gemm_bt(const unsigned short* __restrict__ A,
                                               const unsigned short* __restrict__ Bt,
                                               const float* __restrict__ bias,
                                               void* __restrict__ Cout,
                                               int M, int N, int K) {
    __shared__ __align__(16) unsigned short As[2][128 * 32];
    __shared__ __align__(16) unsigned short Bs[2][128 * 32];

    const int t    = threadIdx.x;
    const int lane = t & 63;
    const int w    = t >> 6;
    const int quad = lane >> 4;
    const int l16  = lane & 15;
    const int wm = (w >> 1) * 64, wn = (w & 1) * 64;

    const int lin = blockIdx.x;
    const int xcd = lin & 7, s = lin >> 3;
    const int n0 = (s >> 2) * 128;
    const int m0 = ((xcd << 2) | (s & 3)) * 128;
    const int rowA = t >> 2, offA = (t & 3) * 8, rowA2 = rowA + 64;

    const size_t aoff0 = (size_t)(m0 + rowA)  * K + offA;
    const size_t aoff1 = (size_t)(m0 + rowA2) * K + offA;
    const size_t boff0 = (size_t)(n0 + rowA)  * K + offA;
    const size_t boff1 = (size_t)(n0 + rowA2) * K + offA;

    // wave-uniform LDS bases (elements): wave w writes [w*512, w*512+512)
    const int wb0 = w * 512, wb1 = 2048 + w * 512;

    f32x4 acc[4][4];
#pragma unroll
    for (int i = 0; i < 4; i++)
#pragma unroll
        for (int j = 0; j < 4; j++) acc[i][j] = (f32x4){0.f, 0.f, 0.f, 0.f};

    // prologue: tile 0 -> LDS[0] via async DMA
    gld16(&A[aoff0],  &As[0][wb0]);
    gld16(&A[aoff1],  &As[0][wb1]);
    gld16(&Bt[boff0], &Bs[0][wb0]);
    gld16(&Bt[boff1], &Bs[0][wb1]);
    __syncthreads();   // drains vmcnt(0)

    int p = 0;
    for (int k0 = 0; k0 < K; k0 += 32, p ^= 1) {
        if (k0 + 32 < K) {   // issue next-tile DMA; latency overlaps MFMAs
            gld16(&A[aoff0 + k0 + 32],  &As[p ^ 1][wb0]);
            gld16(&A[aoff1 + k0 + 32],  &As[p ^ 1][wb1]);
            gld16(&Bt[boff0 + k0 + 32], &Bs[p ^ 1][wb0]);
            gld16(&Bt[boff1 + k0 + 32], &Bs[p ^ 1][wb1]);
        }

        bf16x8 af[4], bfv[4];
#pragma unroll
        for (int i = 0; i < 4; i++)
            af[i] = *(const bf16x8*)&As[p][(wm + i * 16 + l16) * 32 + quad * 8];
#pragma unroll
        for (int j = 0; j < 4; j++)
            bfv[j] = *(const bf16x8*)&Bs[p][(wn + j * 16 + l16) * 32 + quad * 8];
#pragma unroll
        for (int i = 0; i < 4; i++)
#pragma unroll
            for (int j = 0; j < 4; j++)
                acc[i][j] = __builtin_amdgcn_mfma_f32_16x16x32_bf16(af[i], bfv[j], acc[i][j], 0, 0, 0);

        __syncthreads();   // drains next-tile DMA + protects LDS[p] reuse
    }

#pragma unroll
    for (int j = 0; j < 4; j++) {
        int col = n0 + wn + j * 16 + l16;
        float bv = bias[col];
#pragma unroll
        for (int i = 0; i < 4; i++) {
            int rowb = m0 + wm + i * 16 + quad * 4;
#pragma unroll
            for (int r = 0; r < 4; r++) {
                float v = acc[i][j][r] + bv;
                if (RELU) v = fmaxf(v, 0.f);
                if (OUT_BF16)
                    ((unsigned short*)Cout)[(size_t)(rowb + r) * N + col] = f2bf(v);
                else
                    ((float*)Cout)[(size_t)(rowb + r) * N + col] = v;
            }
        }
    }
}

// ---------------------------------------------------------------------------
// Split-K=4 GEMM, global_load_lds staging (same structure); bf16 partials.
// Grid = Nt*32*4 (1-D).
// ---------------------------------------------------------------------------
__global__ __launch_bounds__(256) void gemm_sk4(const unsigned short* __restrict__ A,
                                                const unsigned short* __restrict__ Bt,
                                                unsigned short* __restrict__ P0,
                                                unsigned short* __restrict__ P1,
                                                unsigned short* __restrict__ P2,
                                                unsigned short* __restrict__ P3,
                                                int M, int N, int K, int Nt) {
    __shared__ __align__(16) unsigned short As[2][128 * 32];
    __shared__ __align__(16) unsigned short Bs[2][128 * 32];

    const int t    = threadIdx.x;
    const int lane = t & 63;
    const int w    = t >> 6;
    const int quad = lane >> 4;
    const int l16  = lane & 15;
    const int wm = (w >> 1) * 64, wn = (w & 1) * 64;

    const int lin = blockIdx.x;
    const int xcd = lin & 7, s = lin >> 3;
    const int mi = s & 3;
    const int r  = s >> 2;
    const int n0 = (r % Nt) * 128;
    const int z  = r / Nt;              // 0..3
    const int m0 = ((xcd << 2) | mi) * 128;

    const int K4 = K >> 2;
    const int kbeg = z * K4;
    unsigned short* C = (z == 0) ? P0 : (z == 1) ? P1 : (z == 2) ? P2 : P3;
    const int rowA = t >> 2, offA = (t & 3) * 8, rowA2 = rowA + 64;

    const size_t aoff0 = (size_t)(m0 + rowA)  * K + offA + kbeg;
    const size_t aoff1 = (size_t)(m0 + rowA2) * K + offA + kbeg;
    const size_t boff0 = (size_t)(n0 + rowA)  * K + offA + kbeg;
    const size_t boff1 = (size_t)(n0 + rowA2) * K + offA + kbeg;

    const int wb0 = w * 512, wb1 = 2048 + w * 512;

    f32x4 acc[4][4];
#pragma unroll
    for (int i = 0; i < 4; i++)
#pragma unroll
        for (int j = 0; j < 4; j++) acc[i][j] = (f32x4){0.f, 0.f, 0.f, 0.f};

    gld16(&A[aoff0],  &As[0][wb0]);
    gld16(&A[aoff1],  &As[0][wb1]);
    gld16(&Bt[boff0], &Bs[0][wb0]);
    gld16(&Bt[boff1], &Bs[0][wb1]);
    __syncthreads();

    int p = 0;
    for (int k0 = 0; k0 < K4; k0 += 32, p ^= 1) {
        if (k0 + 32 < K4) {
            gld16(&A[aoff0 + k0 + 32],  &As[p ^ 1][wb0]);
            gld16(&A[aoff1 + k0 + 32],  &As[p ^ 1][wb1]);
            gld16(&Bt[boff0 + k0 + 32], &Bs[p ^ 1][wb0]);
            gld16(&Bt[boff1 + k0 + 32], &Bs[p ^ 1][wb1]);
        }

        bf16x8 af[4], bfv[4];
#pragma unroll
        for (int i = 0; i < 4; i++)
            af[i] = *(const bf16x8*)&As[p][(wm + i * 16 + l16) * 32 + quad * 8];
#pragma unroll
        for (int j = 0; j < 4; j++)
            bfv[j] = *(const bf16x8*)&Bs[p][(wn + j * 16 + l16) * 32 + quad * 8];
#pragma unroll
        for (int i = 0; i < 4; i++)
#pragma unroll
            for (int j = 0; j < 4; j++)
                acc[i][j] = __builtin_amdgcn_mfma_f32_16x16x32_bf16(af[i], bfv[j], acc[i][j], 0, 0, 0);

        __syncthreads();
    }

#pragma unroll
    for (int j = 0; j < 4; j++) {
        int col = n0 + wn + j * 16 + l16;
#pragma unroll
        for (int i = 0; i < 4; i++) {
            int rowb = m0 + wm + i * 16 + quad * 4;
#pragma unroll
            for (int r2 = 0; r2 < 4; r2++)
                C[(size_t)(rowb + r2) * N + col] = f2bf(acc[i][j][r2]);
        }
    }
}

// ---------------------------------------------------------------------------
// MFMA flash attention v5 (unchanged — APAD'ed LDS layout is incompatible
// with global_load_lds's linear destination; keeps register staging).
// ---------------------------------------------------------------------------
__global__ __launch_bounds__(256, 3) void attn_mfma(const unsigned short* __restrict__ qkv,
                                                    const unsigned short* __restrict__ vtg,
                                                    unsigned short* __restrict__ zb) {
    __shared__ __align__(16) unsigned short ks[2][64 * APAD];
    __shared__ __align__(16) unsigned short vt[64 * APAD];
    __shared__ __align__(16) unsigned short ps[128 * APAD];

    const int t    = threadIdx.x;
    const int lane = t & 63;
    const int w    = t >> 6;
    const int l16  = lane & 15;
    const int quad = lane >> 4;

    const int lin  = blockIdx.x;
    const int xcd  = lin & 7;
    const int s    = lin >> 3;
    const int hh   = xcd * 2 + (s & 1);
    const int rest = s >> 1;
    const int b    = rest & 1;
    const int qq0  = rest >> 1;
    const int qq   = b ? qq0 : 15 - qq0;

    const size_t rowbase = (size_t)b * L_;
    const size_t vbase   = ((size_t)(b * H_ + hh) * 64) * (size_t)L_;

    bf16x8 qf[2][2];
#pragma unroll
    for (int g = 0; g < 2; g++) {
        size_t qrow = rowbase + qq * 128 + w * 32 + g * 16 + l16;
#pragma unroll
        for (int c = 0; c < 2; c++)
            qf[g][c] = *(const bf16x8*)&qkv[qrow * 3072 + hh * 64 + c * 32 + quad * 8];
    }

    f32x4 o[2][4];
#pragma unroll
    for (int g = 0; g < 2; g++)
#pragma unroll
        for (int j = 0; j < 4; j++) o[g][j] = (f32x4){0.f, 0.f, 0.f, 0.f};
    float l_i[2][4] = {};

    const int rr0 = t >> 3, o8 = (t & 7) * 8, rr1 = rr0 + 32;
    const int ktmax = 2 * qq + 1;

    {   // preload tile 0
        size_t kg = rowbase * 3072 + 1024 + hh * 64;
        short8 k0 = *(const short8*)&qkv[kg + (size_t)rr0 * 3072 + o8];
        short8 k1 = *(const short8*)&qkv[kg + (size_t)rr1 * 3072 + o8];
        short8 v0 = *(const short8*)&vtg[vbase + (size_t)rr0 * L_ + o8];
        short8 v1 = *(const short8*)&vtg[vbase + (size_t)rr1 * L_ + o8];
        *(short8*)&ks[0][rr0 * APAD + o8] = k0;
        *(short8*)&ks[0][rr1 * APAD + o8] = k1;
        *(short8*)&vt[rr0 * APAD + o8] = v0;
        *(short8*)&vt[rr1 * APAD + o8] = v1;
    }

    short8 kr0, kr1, vr0, vr1;
    for (int kt = 0; kt <= ktmax; kt++) {
        const int p = kt & 1;
        __syncthreads();

        if (kt < ktmax) {
            size_t kg = (rowbase + (kt + 1) * 64) * 3072 + 1024 + hh * 64;
            kr0 = *(const short8*)&qkv[kg + (size_t)rr0 * 3072 + o8];
            kr1 = *(const short8*)&qkv[kg + (size_t)rr1 * 3072 + o8];
            size_t vg = vbase + (kt + 1) * 64;
            vr0 = *(const short8*)&vtg[vg + (size_t)rr0 * L_ + o8];
            vr1 = *(const short8*)&vtg[vg + (size_t)rr1 * L_ + o8];
        }

        f32x4 s4[2][4];
#pragma unroll
        for (int g = 0; g < 2; g++)
#pragma unroll
            for (int j = 0; j < 4; j++) s4[g][j] = (f32x4){0.f, 0.f, 0.f, 0.f};
#pragma unroll
        for (int c = 0; c < 2; c++)
#pragma unroll
            for (int j = 0; j < 4; j++) {
                bf16x8 kf = *(const bf16x8*)&ks[p][(j * 16 + l16) * APAD + c * 32 + quad * 8];
#pragma unroll
                for (int g = 0; g < 2; g++)
                    s4[g][j] = __builtin_amdgcn_mfma_f32_16x16x32_bf16(qf[g][c], kf, s4[g][j], 0, 0, 0);
            }

        if (kt >= 2 * qq) {
#pragma unroll
            for (int g = 0; g < 2; g++)
#pragma unroll
                for (int j = 0; j < 4; j++) {
                    int lk = kt * 64 + j * 16 + l16;
#pragma unroll
                    for (int r = 0; r < 4; r++)
                        if (lk > qq * 128 + w * 32 + g * 16 + quad * 4 + r)
                            s4[g][j][r] = -INFINITY;
                }
        }

#pragma unroll
        for (int g = 0; g < 2; g++)
#pragma unroll
            for (int r = 0; r < 4; r++) {
                float p0 = __builtin_amdgcn_exp2f(s4[g][0][r]);
                float p1 = __builtin_amdgcn_exp2f(s4[g][1][r]);
                float p2 = __builtin_amdgcn_exp2f(s4[g][2][r]);
                float p3 = __builtin_amdgcn_exp2f(s4[g][3][r]);
                l_i[g][r] += (p0 + p1) + (p2 + p3);
                uint2 pk = { pk_trunc(p0, p1), pk_trunc(p2, p3) };
                *(uint2*)&ps[(w * 32 + g * 16 + quad * 4 + r) * APAD + 4 * l16] = pk;
            }

        __builtin_amdgcn_s_waitcnt(0xc07f);

#pragma unroll
        for (int c = 0; c < 2; c++) {
            bf16x8 pf[2];
#pragma unroll
            for (int g = 0; g < 2; g++)
                pf[g] = *(const bf16x8*)&ps[(w * 32 + g * 16 + l16) * APAD + c * 32 + quad * 8];
#pragma unroll
            for (int j = 0; j < 4; j++) {
                bf16x8 vf = *(const bf16x8*)&vt[(j * 16 + l16) * APAD + c * 32 + quad * 8];
#pragma unroll
                for (int g = 0; g < 2; g++)
                    o[g][j] = __builtin_amdgcn_mfma_f32_16x16x32_bf16(pf[g], vf, o[g][j], 0, 0, 0);
            }
        }

        __syncthreads();
        if (kt < ktmax) {
            *(short8*)&ks[p ^ 1][rr0 * APAD + o8] = kr0;
            *(short8*)&ks[p ^ 1][rr1 * APAD + o8] = kr1;
            *(short8*)&vt[rr0 * APAD + o8] = vr0;
            *(short8*)&vt[rr1 * APAD + o8] = vr1;
        }
    }

#pragma unroll
    for (int g = 0; g < 2; g++)
#pragma unroll
        for (int r = 0; r < 4; r++) {
            float l = l_i[g][r];
            l += __shfl_xor(l, 1);
            l += __shfl_xor(l, 2);
            l += __shfl_xor(l, 4);
            l += __shfl_xor(l, 8);
            float inv = 1.f / l;
            size_t row = rowbase + qq * 128 + w * 32 + g * 16 + quad * 4 + r;
#pragma unroll
            for (int j = 0; j < 4; j++)
                zb[row * 1024 + hh * 64 + j * 16 + l16] = f2bf(o[g][j][r] * inv);
        }
}

// ---------------------------------------------------------------------------
// LayerNorm(a + sum of 4 bf16 partial planes + bias) * g + beta.
// ---------------------------------------------------------------------------
template <int WRITE_BF16>
__global__ __launch_bounds__(256) void ln5_kernel(const float* __restrict__ a,
                                                  const unsigned short* __restrict__ q0,
                                                  const unsigned short* __restrict__ q1,
                                                  const unsigned short* __restrict__ q2,
                                                  const unsigned short* __restrict__ q3,
                                                  const float* __restrict__ bias,
                                                  const float* __restrict__ g,
                                                  const float* __restrict__ be,
                                                  float* __restrict__ out,
                                                  unsigned short* __restrict__ out_bf) {
    __shared__ float s1[256], s2[256];
    const int row = blockIdx.x;
    const int t   = threadIdx.x;
    const size_t base = (size_t)row * E_ + t * 4;

    float4 ya = *(const float4*)&a[base];
    ushort4 u0 = *(const ushort4*)&q0[base];
    ushort4 u1 = *(const ushort4*)&q1[base];
    ushort4 u2 = *(const ushort4*)&q2[base];
    ushort4 u3 = *(const ushort4*)&q3[base];
    float4 bb = *(const float4*)&bias[t * 4];
    float y0 = ya.x + bb.x + bf2f(u0.x) + bf2f(u1.x) + bf2f(u2.x) + bf2f(u3.x);
    float y1 = ya.y + bb.y + bf2f(u0.y) + bf2f(u1.y) + bf2f(u2.y) + bf2f(u3.y);
    float y2 = ya.z + bb.z + bf2f(u0.z) + bf2f(u1.z) + bf2f(u2.z) + bf2f(u3.z);
    float y3 = ya.w + bb.w + bf2f(u0.w) + bf2f(u1.w) + bf2f(u2.w) + bf2f(u3.w);

    s1[t] = y0 + y1 + y2 + y3;
    s2[t] = y0 * y0 + y1 * y1 + y2 * y2 + y3 * y3;
    __syncthreads();
    for (int off = 128; off > 0; off >>= 1) {
        if (t < off) { s1[t] += s1[t + off]; s2[t] += s2[t + off]; }
        __syncthreads();
    }
    float mean = s1[0] * (1.0f / E_);
    float var  = s2[0] * (1.0f / E_) - mean * mean;
    float rstd = rsqrtf(var + 1e-5f);

    float4 gv = *(const float4*)&g[t * 4];
    float4 bv = *(const float4*)&be[t * 4];
    float4 ov;
    ov.x = (y0 - mean) * rstd * gv.x + bv.x;
    ov.y = (y1 - mean) * rstd * gv.y + bv.y;
    ov.z = (y2 - mean) * rstd * gv.z + bv.z;
    ov.w = (y3 - mean) * rstd * gv.w + bv.w;
    *(float4*)&out[base] = ov;
    if (WRITE_BF16) {
        ushort4 pk = { f2bf(ov.x), f2bf(ov.y), f2bf(ov.z), f2bf(ov.w) };
        *(ushort4*)&out_bf[base] = pk;
    }
}

// ---------------------------------------------------------------------------
extern "C" void kernel_launch(void* const* d_in, const int* in_sizes, int n_in,
                              void* d_out, int out_size, void* d_ws, size_t ws_size,
                              hipStream_t stream)
{
    const float* x     = (const float*)d_in[0];
    const float* Wq    = (const float*)d_in[2];
    const float* bq    = (const float*)d_in[3];
    const float* Wk    = (const float*)d_in[4];
    const float* bk    = (const float*)d_in[5];
    const float* Wv    = (const float*)d_in[6];
    const float* bv    = (const float*)d_in[7];
    const float* Wo    = (const float*)d_in[8];
    const float* bo    = (const float*)d_in[9];
    const float* W1    = (const float*)d_in[10];
    const float* c1    = (const float*)d_in[11];
    const float* W2    = (const float*)d_in[12];
    const float* c2    = (const float*)d_in[13];
    const float* g1    = (const float*)d_in[14];
    const float* beta1 = (const float*)d_in[15];
    const float* g2    = (const float*)d_in[16];
    const float* beta2 = (const float*)d_in[17];
    float* out = (float*)d_out;

    const size_t MB = 1024 * 1024;
    char* w = (char*)d_ws;
    unsigned short* xb    = (unsigned short*)(w + 0 * MB);    // [0,8)   prep..QKV
    unsigned short* Wqkvt = (unsigned short*)(w + 8 * MB);    // [8,14)
    unsigned short* Wot   = (unsigned short*)(w + 14 * MB);   // [14,16)
    unsigned short* W1t   = (unsigned short*)(w + 16 * MB);   // [16,24)
    unsigned short* W2t   = (unsigned short*)(w + 24 * MB);   // [24,32)
    float*          bqkv  = (float*)(w + 32 * MB);            // [32,33)
    unsigned short* qkv   = (unsigned short*)(w + 33 * MB);   // [33,57)  QKV..attn
    unsigned short* zb    = (unsigned short*)(w + 57 * MB);   // [57,65)  attn..Wo
    float*          h     = (float*)(w + 65 * MB);            // [65,81)  LN1..LN2
    unsigned short* vtg   = (unsigned short*)(w + 89 * MB);   // [89,97)  vT..attn
    // Wo partials (bf16, 8 MB each): over dead qkv + dead vtg
    unsigned short* ap0   = (unsigned short*)(w + 33 * MB);
    unsigned short* ap1   = (unsigned short*)(w + 41 * MB);
    unsigned short* ap2   = (unsigned short*)(w + 49 * MB);
    unsigned short* ap3   = (unsigned short*)(w + 89 * MB);
    unsigned short* hb    = (unsigned short*)(w + 0 * MB);    // LN1..FFN1 (over xb)
    unsigned short* ff1b  = (unsigned short*)(w + 33 * MB);   // FFN1..FFN2 [33,65)
    // FFN2 partials (bf16): over dead hb/Wqkvt/Wot/W1t + tail
    unsigned short* fp0   = (unsigned short*)(w + 0 * MB);
    unsigned short* fp1   = (unsigned short*)(w + 8 * MB);
    unsigned short* fp2   = (unsigned short*)(w + 16 * MB);
    unsigned short* fp3   = (unsigned short*)(w + 81 * MB);

    dim3 blk(256);

    prep<<<dim3(16396), blk, 0, stream>>>(x, Wq, Wk, Wv, bq, bk, bv, Wo, W1, W2,
                                          xb, Wqkvt, Wot, W1t, W2t, bqkv);

    // QKV: N=3072 -> 24 n-tiles, grid 24*32 = 768
    gemm_bt<0, 1><<<dim3(768), blk, 0, stream>>>(xb, Wqkvt, bqkv, qkv, M_, 3072, E_);

    v_transpose_perm<<<dim3(L_ / 64, H_, B_), blk, 0, stream>>>(qkv, vtg);

    attn_mfma<<<dim3(512), blk, 0, stream>>>(qkv, vtg, zb);

    // Wo: N=1024 -> 8 n-tiles, split-K=4, grid 8*32*4 = 1024
    gemm_sk4<<<dim3(1024), blk, 0, stream>>>(zb, Wot, ap0, ap1, ap2, ap3, M_, E_, E_, 8);

    ln5_kernel<1><<<dim3(M_), blk, 0, stream>>>(x, ap0, ap1, ap2, ap3, bo, g1, beta1, h, hb);

    // FFN1: N=4096 -> 32 n-tiles, grid 32*32 = 1024
    gemm_bt<1, 1><<<dim3(1024), blk, 0, stream>>>(hb, W1t, c1, ff1b, M_, DFF, E_);

    // FFN2: N=1024 -> 8 n-tiles, split-K=4, grid 1024
    gemm_sk4<<<dim3(1024), blk, 0, stream>>>(ff1b, W2t, fp0, fp1, fp2, fp3, M_, E_, DFF, 8);

    ln5_kernel<0><<<dim3(M_), blk, 0, stream>>>(h, fp0, fp1, fp2, fp3, c2, g2, beta2, out, nullptr);
}

// Round 2
// 341.265 us; speedup vs baseline: 1.1053x; 1.1053x over previous
//
#include <hip/hip_runtime.h>
#include <hip/hip_bf16.h>
#include <math.h>

#define B_   2
#define L_   2048
#define E_   1024
#define H_   16
#define DH   64
#define DFF  4096
#define M_   4096
#define APAD 72
#define SCALE_Q 0.18033688011112042f   // log2(e)/8, folded into Wq/bq

typedef __attribute__((ext_vector_type(8))) short short8;
typedef __attribute__((ext_vector_type(4))) float f32x4;
typedef __bf16 bf16x8 __attribute__((ext_vector_type(8)));

__device__ __forceinline__ float bf2f(unsigned short u) {
    return __uint_as_float(((unsigned)u) << 16);
}
__device__ __forceinline__ unsigned short f2bf(float f) {
    unsigned u = __float_as_uint(f);
    return (unsigned short)((u + 0x7fff + ((u >> 16) & 1)) >> 16);
}
__device__ __forceinline__ unsigned pk_trunc(float lo, float hi) {
    return (__float_as_uint(lo) >> 16) | (__float_as_uint(hi) & 0xffff0000u);
}

// Async global->LDS, 16B/lane. LDS dest = wave-uniform base + lane*16B.
__device__ __forceinline__ void gld16(const unsigned short* g, unsigned short* l) {
    __builtin_amdgcn_global_load_lds(
        (const __attribute__((address_space(1))) void*)g,
        (__attribute__((address_space(3))) void*)l, 16, 0, 0);
}

// ---------------------------------------------------------------------------
// Fused preprocessing (unchanged).
// ---------------------------------------------------------------------------
__global__ __launch_bounds__(256) void prep(const float* __restrict__ x,
                                            const float* __restrict__ Wq,
                                            const float* __restrict__ Wk,
                                            const float* __restrict__ Wv,
                                            const float* __restrict__ bq,
                                            const float* __restrict__ bk,
                                            const float* __restrict__ bv,
                                            const float* __restrict__ Wo,
                                            const float* __restrict__ W1,
                                            const float* __restrict__ W2,
                                            unsigned short* __restrict__ xb,
                                            unsigned short* __restrict__ Wqkvt,
                                            unsigned short* __restrict__ Wot,
                                            unsigned short* __restrict__ W1t,
                                            unsigned short* __restrict__ W2t,
                                            float* __restrict__ bqkv) {
    __shared__ float tile[32][33];
    int bid = blockIdx.x;
    const int t = threadIdx.x;

    if (bid < 4096) {                      // x -> bf16
        int i = (bid * 256 + t) * 4;
        float4 v = *(const float4*)&x[i];
        ushort4 pk = { f2bf(v.x), f2bf(v.y), f2bf(v.z), f2bf(v.w) };
        *(ushort4*)&xb[i] = pk;
        return;
    }
    bid -= 4096;

    const float* in; unsigned short* outp; int R, C, r0, c0; float sc = 1.f;
    if (bid < 3072) {                      // Wqkv: per-head [E][DH] -> [DH][E]
        int xq = bid & 1, yq = (bid >> 1) & 31, wh = bid >> 6;
        int which = wh >> 4, h = wh & 15;
        in   = (which == 0 ? Wq : which == 1 ? Wk : Wv) + (size_t)h * E_ * DH;
        outp = Wqkvt + ((size_t)which * 1024 + h * 64) * 1024;
        R = E_; C = DH; r0 = yq * 32; c0 = xq * 32;
        if (which == 0) sc = SCALE_Q;
    } else if (bid < 4096) {               // Wo [E][E]
        bid -= 3072;
        in = Wo; outp = Wot; R = E_; C = E_;
        c0 = (bid & 31) * 32; r0 = (bid >> 5) * 32;
    } else if (bid < 8192) {               // W1 [E][DFF]
        bid -= 4096;
        in = W1; outp = W1t; R = E_; C = DFF;
        c0 = (bid & 127) * 32; r0 = (bid >> 7) * 32;
    } else if (bid < 12288) {              // W2 [DFF][E]
        bid -= 8192;
        in = W2; outp = W2t; R = DFF; C = E_;
        c0 = (bid & 31) * 32; r0 = (bid >> 5) * 32;
    } else {                               // bqkv
        bid -= 12288;
        int n = bid * 256 + t;
        bqkv[n] = n < 1024 ? bq[n] * SCALE_Q : n < 2048 ? bk[n - 1024] : bv[n - 2048];
        return;
    }

    const int tx = t & 31, tq = t >> 5;
#pragma unroll
    for (int s2 = 0; s2 < 4; s2++)
        tile[tq * 4 + s2][tx] = in[(size_t)(r0 + tq * 4 + s2) * C + c0 + tx] * sc;
    __syncthreads();
#pragma unroll
    for (int s2 = 0; s2 < 4; s2++)
        outp[(size_t)(c0 + tq * 4 + s2) * R + r0 + tx] = f2bf(tile[tx][tq * 4 + s2]);
}

// ---------------------------------------------------------------------------
// V pre-transpose with pi-permuted columns (unchanged).
// ---------------------------------------------------------------------------
__global__ __launch_bounds__(256) void v_transpose_perm(const unsigned short* __restrict__ qkv,
                                                        unsigned short* __restrict__ vtg) {
    __shared__ unsigned short tile[64 * APAD];
    const int t  = threadIdx.x;
    const int kt = blockIdx.x, hh = blockIdx.y, b = blockIdx.z;
    const int rr0 = t >> 3, o8 = (t & 7) * 8, rr1 = rr0 + 32;
    const size_t gbase = ((size_t)b * L_ + kt * 64) * 3072 + 2048 + hh * 64;
    *(short8*)&tile[rr0 * APAD + o8] = *(const short8*)&qkv[gbase + (size_t)rr0 * 3072 + o8];
    *(short8*)&tile[rr1 * APAD + o8] = *(const short8*)&qkv[gbase + (size_t)rr1 * 3072 + o8];
    __syncthreads();
    const size_t obase = ((size_t)(b * H_ + hh) * 64) * (size_t)L_ + kt * 64;
    const int a = t & 15, d0 = (t >> 4) * 4;
#pragma unroll
    for (int s2 = 0; s2 < 4; s2++) {
        int d = d0 + s2;
        ushort4 pk = { tile[(a +  0) * APAD + d], tile[(a + 16) * APAD + d],
                       tile[(a + 32) * APAD + d], tile[(a + 48) * APAD + d] };
        *(ushort4*)&vtg[obase + (size_t)d * L_ + 4 * a] = pk;
    }
}

// ---------------------------------------------------------------------------
// 256x256 8-phase bf16 GEMM (m201 template, plain HIP).
//   BM=BN=256, BK=64, 8 waves (2Mx4N), 512 threads, 128 KiB LDS
//   (2 K-tile double-buffer x {A,B} x 256x64).
// Per K-tile: 4 phases over block-C quadrants (qr,qc):
//   P1 (0,0): reads A-half0 + B-half0   P2 (0,1): A-half0 + B-half1
//   P3 (1,0): A-half1 + B-half0         P4 (1,1): A-half1 + B-half1
// Staging (1 half-tile = 2 gld16/wave per phase):
//   P1: B1(u+1)->buf[u+1]   P2: A1(u+1)->buf[u+1]
//   P3: A0(u+2)->buf[u]     P4: B0(u+2)->buf[u]
// Safety: A-half0 of tile u last read P2(u) (reads drained by lgkmcnt(0)
// before barrier2(P2)); its slot re-staged P3(u). B-half0 last read P3,
// restaged P4. vmcnt(4) at P4 completes all 4 halves of tile u+1
// (outstanding there = B1(u+1),A1(u+1),A0(u+2),B0(u+2) = 8 loads/wave).
// Swizzle: chunk' = chunk ^ (row&7) -> conflict-free ds_read_b128; applied
// as inverse-swizzled GLOBAL source + swizzled read (linear LDS dest, G4/#21).
// ---------------------------------------------------------------------------
#define BAR() __builtin_amdgcn_s_barrier()
#define LGKM0() do { asm volatile("s_waitcnt lgkmcnt(0)" ::: "memory"); \
                     __builtin_amdgcn_sched_barrier(0); } while (0)

#define G256_READ_A(qr) do {                                                  \
    _Pragma("unroll") for (int mi = 0; mi < 4; mi++)                          \
    _Pragma("unroll") for (int ks = 0; ks < 2; ks++)                          \
        afr[mi][ks] = *(const bf16x8*)&As[bb + ((qr) * 128 + aRow + mi * 16) * 64 + (ks ? cs1 : cs0)]; \
} while (0)

#define G256_READ_B(qc) do {                                                  \
    _Pragma("unroll") for (int nj = 0; nj < 2; nj++)                          \
    _Pragma("unroll") for (int ks = 0; ks < 2; ks++)                          \
        bfr[qc][nj][ks] = *(const bf16x8*)&Bs[bb + ((qc) * 128 + bRow + nj * 16) * 64 + (ks ? cs1 : cs0)]; \
} while (0)

#define G256_MFMA(qr, qc) do {                                                \
    __builtin_amdgcn_s_setprio(1);                                            \
    _Pragma("unroll") for (int mi = 0; mi < 4; mi++)                          \
    _Pragma("unroll") for (int nj = 0; nj < 2; nj++)                          \
    _Pragma("unroll") for (int ks = 0; ks < 2; ks++)                          \
        acc[qr][qc][mi][nj] = __builtin_amdgcn_mfma_f32_16x16x32_bf16(        \
            afr[mi][ks], bfr[qc][nj][ks], acc[qr][qc][mi][nj], 0, 0, 0);      \
    __builtin_amdgcn_s_setprio(0);                                            \
} while (0)

template <int RELU, int SK>
__global__ __launch_bounds__(512, 2) void gemm256(const unsigned short* __restrict__ A,
                                                  const unsigned short* __restrict__ Bt,
                                                  const float* __restrict__ bias,
                                                  unsigned short* __restrict__ P0,
                                                  unsigned short* __restrict__ P1,
                                                  unsigned short* __restrict__ P2,
                                                  unsigned short* __restrict__ P3,
                                                  int M, int N, int K) {
    extern __shared__ __align__(16) unsigned short g_lds[];
    unsigned short* As = g_lds;            // [2][256][64] elems
    unsigned short* Bs = g_lds + 32768;    // [2][256][64] elems

    const int t    = threadIdx.x;
    const int lane = t & 63;
    const int w    = t >> 6;
    const int quad = lane >> 4;
    const int l16  = lane & 15;

    const int lin = blockIdx.x;
    const int xcd = lin & 7, s = lin >> 3;
    const int m0 = ((xcd << 1) | (s & 1)) * 256;
    const int rest = s >> 1;
    int n0, kbeg, KT;
    unsigned short* C;
    if (SK) {                       // N=1024 -> 4 n-tiles, split-K=4
        n0 = (rest & 3) * 256;
        const int z  = rest >> 2;
        const int K4 = K >> 2;
        kbeg = z * K4;
        KT   = K4 >> 6;
        C = (z == 0) ? P0 : (z == 1) ? P1 : (z == 2) ? P2 : P3;
    } else {
        n0 = rest * 256;
        kbeg = 0;
        KT   = K >> 6;
        C = P0;
    }

    // ---- staging addressing: thread t covers (row = L*64 + (t>>3), slot t&7)
    // of a 128x64 half-tile; global k-chunk = slot ^ (row&7) (inverse swizzle)
    const int srow = t >> 3;
    const int ksw  = ((t & 7) ^ (srow & 7)) * 8;
    const size_t aStage = (size_t)(m0 + srow) * K + kbeg + ksw;
    const size_t bStage = (size_t)(n0 + srow) * K + kbeg + ksw;

    auto stageA = [&](int buf, int h, int v) {
        size_t g = aStage + (size_t)(h * 128) * K + (size_t)v * 64;
        unsigned short* l = As + buf * 16384 + h * 8192 + w * 512;
        gld16(A + g, l);
        gld16(A + g + (size_t)64 * K, l + 4096);
    };
    auto stageB = [&](int buf, int h, int v) {
        size_t g = bStage + (size_t)(h * 128) * K + (size_t)v * 64;
        unsigned short* l = Bs + buf * 16384 + h * 8192 + w * 512;
        gld16(Bt + g, l);
        gld16(Bt + g + (size_t)64 * K, l + 4096);
    };

    // ---- fragment read addressing (swizzled chunk, free of bank conflicts)
    const int aRow = (w >> 2) * 64 + l16;   // within A half-block
    const int bRow = (w & 3) * 32 + l16;    // within B half-block
    const int cs0  = (quad ^ (l16 & 7)) * 8;
    const int cs1  = cs0 ^ 32;

    f32x4 acc[2][2][4][2];
#pragma unroll
    for (int a1 = 0; a1 < 2; a1++)
#pragma unroll
        for (int a2 = 0; a2 < 2; a2++)
#pragma unroll
            for (int a3 = 0; a3 < 4; a3++)
#pragma unroll
                for (int a4 = 0; a4 < 2; a4++)
                    acc[a1][a2][a3][a4] = (f32x4){0.f, 0.f, 0.f, 0.f};

    bf16x8 afr[4][2], bfr[2][2][2];

    // ---- prologue: tile0 (all 4 halves) + tile1 A0,B0; wait tile0 only
    stageA(0, 0, 0); stageA(0, 1, 0); stageB(0, 0, 0); stageB(0, 1, 0);
    if (KT > 1) {
        stageA(1, 0, 1); stageB(1, 0, 1);
        asm volatile("s_waitcnt vmcnt(4)" ::: "memory");
    } else {
        asm volatile("s_waitcnt vmcnt(0)" ::: "memory");
    }
    BAR();

    for (int u = 0; u < KT; ++u) {
        const int bb = (u & 1) * 16384;
        const int nb = ((u + 1) & 1);

        // ---- P1 (0,0)
        G256_READ_A(0);
        G256_READ_B(0);
        if (u + 1 < KT) stageB(nb, 1, u + 1);        // B1(u+1)
        BAR(); LGKM0();
        G256_MFMA(0, 0);
        BAR();

        // ---- P2 (0,1)
        G256_READ_B(1);
        if (u + 1 < KT) stageA(nb, 1, u + 1);        // A1(u+1)
        BAR(); LGKM0();
        G256_MFMA(0, 1);
        BAR();

        // ---- P3 (1,0)
        G256_READ_A(1);
        if (u + 2 < KT) stageA(u & 1, 0, u + 2);     // A0(u+2) -> buf[u&1]
        BAR(); LGKM0();
        G256_MFMA(1, 0);
        BAR();

        // ---- P4 (1,1)
        if (u + 2 < KT) {
            stageB(u & 1, 0, u + 2);                 // B0(u+2) -> buf[u&1]
            asm volatile("s_waitcnt vmcnt(4)" ::: "memory");
        } else {
            asm volatile("s_waitcnt vmcnt(0)" ::: "memory");
        }
        BAR(); LGKM0();
        G256_MFMA(1, 1);
        BAR();
    }

    // ---- epilogue
#pragma unroll
    for (int qr = 0; qr < 2; qr++)
#pragma unroll
        for (int qc = 0; qc < 2; qc++)
#pragma unroll
            for (int nj = 0; nj < 2; nj++) {
                const int col = n0 + qc * 128 + (w & 3) * 32 + nj * 16 + l16;
                const float bv = SK ? 0.f : bias[col];
#pragma unroll
                for (int mi = 0; mi < 4; mi++) {
                    const int row = m0 + qr * 128 + (w >> 2) * 64 + mi * 16 + quad * 4;
#pragma unroll
                    for (int r = 0; r < 4; r++) {
                        float v = acc[qr][qc][mi][nj][r] + bv;
                        if (RELU) v = fmaxf(v, 0.f);
                        C[(size_t)(row + r) * N + col] = f2bf(v);
                    }
                }
            }
}

// ---------------------------------------------------------------------------
// MFMA flash attention v5 (unchanged).
// ---------------------------------------------------------------------------
__global__ __launch_bounds__(256, 3) void attn_mfma(const unsigned short* __restrict__ qkv,
                                                    const unsigned short* __restrict__ vtg,
                                                    unsigned short* __restrict__ zb) {
    __shared__ __align__(16) unsigned short ks[2][64 * APAD];
    __shared__ __align__(16) unsigned short vt[64 * APAD];
    __shared__ __align__(16) unsigned short ps[128 * APAD];

    const int t    = threadIdx.x;
    const int lane = t & 63;
    const int w    = t >> 6;
    const int l16  = lane & 15;
    const int quad = lane >> 4;

    const int lin  = blockIdx.x;
    const int xcd  = lin & 7;
    const int s    = lin >> 3;
    const int hh   = xcd * 2 + (s & 1);
    const int rest = s >> 1;
    const int b    = rest & 1;
    const int qq0  = rest >> 1;
    const int qq   = b ? qq0 : 15 - qq0;

    const size_t rowbase = (size_t)b * L_;
    const size_t vbase   = ((size_t)(b * H_ + hh) * 64) * (size_t)L_;

    bf16x8 qf[2][2];
#pragma unroll
    for (int g = 0; g < 2; g++) {
        size_t qrow = rowbase + qq * 128 + w * 32 + g * 16 + l16;
#pragma unroll
        for (int c = 0; c < 2; c++)
            qf[g][c] = *(const bf16x8*)&qkv[qrow * 3072 + hh * 64 + c * 32 + quad * 8];
    }

    f32x4 o[2][4];
#pragma unroll
    for (int g = 0; g < 2; g++)
#pragma unroll
        for (int j = 0; j < 4; j++) o[g][j] = (f32x4){0.f, 0.f, 0.f, 0.f};
    float l_i[2][4] = {};

    const int rr0 = t >> 3, o8 = (t & 7) * 8, rr1 = rr0 + 32;
    const int ktmax = 2 * qq + 1;

    {   // preload tile 0
        size_t kg = rowbase * 3072 + 1024 + hh * 64;
        short8 k0 = *(const short8*)&qkv[kg + (size_t)rr0 * 3072 + o8];
        short8 k1 = *(const short8*)&qkv[kg + (size_t)rr1 * 3072 + o8];
        short8 v0 = *(const short8*)&vtg[vbase + (size_t)rr0 * L_ + o8];
        short8 v1 = *(const short8*)&vtg[vbase + (size_t)rr1 * L_ + o8];
        *(short8*)&ks[0][rr0 * APAD + o8] = k0;
        *(short8*)&ks[0][rr1 * APAD + o8] = k1;
        *(short8*)&vt[rr0 * APAD + o8] = v0;
        *(short8*)&vt[rr1 * APAD + o8] = v1;
    }

    short8 kr0, kr1, vr0, vr1;
    for (int kt = 0; kt <= ktmax; kt++) {
        const int p = kt & 1;
        __syncthreads();

        if (kt < ktmax) {
            size_t kg = (rowbase + (kt + 1) * 64) * 3072 + 1024 + hh * 64;
            kr0 = *(const short8*)&qkv[kg + (size_t)rr0 * 3072 + o8];
            kr1 = *(const short8*)&qkv[kg + (size_t)rr1 * 3072 + o8];
            size_t vg = vbase + (kt + 1) * 64;
            vr0 = *(const short8*)&vtg[vg + (size_t)rr0 * L_ + o8];
            vr1 = *(const short8*)&vtg[vg + (size_t)rr1 * L_ + o8];
        }

        f32x4 s4[2][4];
#pragma unroll
        for (int g = 0; g < 2; g++)
#pragma unroll
            for (int j = 0; j < 4; j++) s4[g][j] = (f32x4){0.f, 0.f, 0.f, 0.f};
#pragma unroll
        for (int c = 0; c < 2; c++)
#pragma unroll
            for (int j = 0; j < 4; j++) {
                bf16x8 kf = *(const bf16x8*)&ks[p][(j * 16 + l16) * APAD + c * 32 + quad * 8];
#pragma unroll
                for (int g = 0; g < 2; g++)
                    s4[g][j] = __builtin_amdgcn_mfma_f32_16x16x32_bf16(qf[g][c], kf, s4[g][j], 0, 0, 0);
            }

        if (kt >= 2 * qq) {
#pragma unroll
            for (int g = 0; g < 2; g++)
#pragma unroll
                for (int j = 0; j < 4; j++) {
                    int lk = kt * 64 + j * 16 + l16;
#pragma unroll
                    for (int r = 0; r < 4; r++)
                        if (lk > qq * 128 + w * 32 + g * 16 + quad * 4 + r)
                            s4[g][j][r] = -INFINITY;
                }
        }

#pragma unroll
        for (int g = 0; g < 2; g++)
#pragma unroll
            for (int r = 0; r < 4; r++) {
                float p0 = __builtin_amdgcn_exp2f(s4[g][0][r]);
                float p1 = __builtin_amdgcn_exp2f(s4[g][1][r]);
                float p2 = __builtin_amdgcn_exp2f(s4[g][2][r]);
                float p3 = __builtin_amdgcn_exp2f(s4[g][3][r]);
                l_i[g][r] += (p0 + p1) + (p2 + p3);
                uint2 pk = { pk_trunc(p0, p1), pk_trunc(p2, p3) };
                *(uint2*)&ps[(w * 32 + g * 16 + quad * 4 + r) * APAD + 4 * l16] = pk;
            }

        __builtin_amdgcn_s_waitcnt(0xc07f);

#pragma unroll
        for (int c = 0; c < 2; c++) {
            bf16x8 pf[2];
#pragma unroll
            for (int g = 0; g < 2; g++)
                pf[g] = *(const bf16x8*)&ps[(w * 32 + g * 16 + l16) * APAD + c * 32 + quad * 8];
#pragma unroll
            for (int j = 0; j < 4; j++) {
                bf16x8 vf = *(const bf16x8*)&vt[(j * 16 + l16) * APAD + c * 32 + quad * 8];
#pragma unroll
                for (int g = 0; g < 2; g++)
                    o[g][j] = __builtin_amdgcn_mfma_f32_16x16x32_bf16(pf[g], vf, o[g][j], 0, 0, 0);
            }
        }

        __syncthreads();
        if (kt < ktmax) {
            *(short8*)&ks[p ^ 1][rr0 * APAD + o8] = kr0;
            *(short8*)&ks[p ^ 1][rr1 * APAD + o8] = kr1;
            *(short8*)&vt[rr0 * APAD + o8] = vr0;
            *(short8*)&vt[rr1 * APAD + o8] = vr1;
        }
    }

#pragma unroll
    for (int g = 0; g < 2; g++)
#pragma unroll
        for (int r = 0; r < 4; r++) {
            float l = l_i[g][r];
            l += __shfl_xor(l, 1);
            l += __shfl_xor(l, 2);
            l += __shfl_xor(l, 4);
            l += __shfl_xor(l, 8);
            float inv = 1.f / l;
            size_t row = rowbase + qq * 128 + w * 32 + g * 16 + quad * 4 + r;
#pragma unroll
            for (int j = 0; j < 4; j++)
                zb[row * 1024 + hh * 64 + j * 16 + l16] = f2bf(o[g][j][r] * inv);
        }
}

// ---------------------------------------------------------------------------
// LayerNorm(a + sum of 4 bf16 partial planes + bias) * g + beta.
// ---------------------------------------------------------------------------
template <int WRITE_BF16>
__global__ __launch_bounds__(256) void ln5_kernel(const float* __restrict__ a,
                                                  const unsigned short* __restrict__ q0,
                                                  const unsigned short* __restrict__ q1,
                                                  const unsigned short* __restrict__ q2,
                                                  const unsigned short* __restrict__ q3,
                                                  const float* __restrict__ bias,
                                                  const float* __restrict__ g,
                                                  const float* __restrict__ be,
                                                  float* __restrict__ out,
                                                  unsigned short* __restrict__ out_bf) {
    __shared__ float s1[256], s2[256];
    const int row = blockIdx.x;
    const int t   = threadIdx.x;
    const size_t base = (size_t)row * E_ + t * 4;

    float4 ya = *(const float4*)&a[base];
    ushort4 u0 = *(const ushort4*)&q0[base];
    ushort4 u1 = *(const ushort4*)&q1[base];
    ushort4 u2 = *(const ushort4*)&q2[base];
    ushort4 u3 = *(const ushort4*)&q3[base];
    float4 bb = *(const float4*)&bias[t * 4];
    float y0 = ya.x + bb.x + bf2f(u0.x) + bf2f(u1.x) + bf2f(u2.x) + bf2f(u3.x);
    float y1 = ya.y + bb.y + bf2f(u0.y) + bf2f(u1.y) + bf2f(u2.y) + bf2f(u3.y);
    float y2 = ya.z + bb.z + bf2f(u0.z) + bf2f(u1.z) + bf2f(u2.z) + bf2f(u3.z);
    float y3 = ya.w + bb.w + bf2f(u0.w) + bf2f(u1.w) + bf2f(u2.w) + bf2f(u3.w);

    s1[t] = y0 + y1 + y2 + y3;
    s2[t] = y0 * y0 + y1 * y1 + y2 * y2 + y3 * y3;
    __syncthreads();
    for (int off = 128; off > 0; off >>= 1) {
        if (t < off) { s1[t] += s1[t + off]; s2[t] += s2[t + off]; }
        __syncthreads();
    }
    float mean = s1[0] * (1.0f / E_);
    float var  = s2[0] * (1.0f / E_) - mean * mean;
    float rstd = rsqrtf(var + 1e-5f);

    float4 gv = *(const float4*)&g[t * 4];
    float4 bv = *(const float4*)&be[t * 4];
    float4 ov;
    ov.x = (y0 - mean) * rstd * gv.x + bv.x;
    ov.y = (y1 - mean) * rstd * gv.y + bv.y;
    ov.z = (y2 - mean) * rstd * gv.z + bv.z;
    ov.w = (y3 - mean) * rstd * gv.w + bv.w;
    *(float4*)&out[base] = ov;
    if (WRITE_BF16) {
        ushort4 pk = { f2bf(ov.x), f2bf(ov.y), f2bf(ov.z), f2bf(ov.w) };
        *(ushort4*)&out_bf[base] = pk;
    }
}

// ---------------------------------------------------------------------------
extern "C" void kernel_launch(void* const* d_in, const int* in_sizes, int n_in,
                              void* d_out, int out_size, void* d_ws, size_t ws_size,
                              hipStream_t stream)
{
    const float* x     = (const float*)d_in[0];
    const float* Wq    = (const float*)d_in[2];
    const float* bq    = (const float*)d_in[3];
    const float* Wk    = (const float*)d_in[4];
    const float* bk    = (const float*)d_in[5];
    const float* Wv    = (const float*)d_in[6];
    const float* bv    = (const float*)d_in[7];
    const float* Wo    = (const float*)d_in[8];
    const float* bo    = (const float*)d_in[9];
    const float* W1    = (const float*)d_in[10];
    const float* c1    = (const float*)d_in[11];
    const float* W2    = (const float*)d_in[12];
    const float* c2    = (const float*)d_in[13];
    const float* g1    = (const float*)d_in[14];
    const float* beta1 = (const float*)d_in[15];
    const float* g2    = (const float*)d_in[16];
    const float* beta2 = (const float*)d_in[17];
    float* out = (float*)d_out;

    const size_t MB = 1024 * 1024;
    char* w = (char*)d_ws;
    unsigned short* xb    = (unsigned short*)(w + 0 * MB);    // [0,8)   prep..QKV
    unsigned short* Wqkvt = (unsigned short*)(w + 8 * MB);    // [8,14)
    unsigned short* Wot   = (unsigned short*)(w + 14 * MB);   // [14,16)
    unsigned short* W1t   = (unsigned short*)(w + 16 * MB);   // [16,24)
    unsigned short* W2t   = (unsigned short*)(w + 24 * MB);   // [24,32)
    float*          bqkv  = (float*)(w + 32 * MB);            // [32,33)
    unsigned short* qkv   = (unsigned short*)(w + 33 * MB);   // [33,57)  QKV..attn
    unsigned short* zb    = (unsigned short*)(w + 57 * MB);   // [57,65)  attn..Wo
    float*          h     = (float*)(w + 65 * MB);            // [65,81)  LN1..LN2
    unsigned short* vtg   = (unsigned short*)(w + 89 * MB);   // [89,97)  vT..attn
    // Wo partials (bf16, 8 MB each): over dead qkv + dead vtg
    unsigned short* ap0   = (unsigned short*)(w + 33 * MB);
    unsigned short* ap1   = (unsigned short*)(w + 41 * MB);
    unsigned short* ap2   = (unsigned short*)(w + 49 * MB);
    unsigned short* ap3   = (unsigned short*)(w + 89 * MB);
    unsigned short* hb    = (unsigned short*)(w + 0 * MB);    // LN1..FFN1 (over xb)
    unsigned short* ff1b  = (unsigned short*)(w + 33 * MB);   // FFN1..FFN2 [33,65)
    // FFN2 partials (bf16): over dead hb/Wqkvt/Wot/W1t + tail
    unsigned short* fp0   = (unsigned short*)(w + 0 * MB);
    unsigned short* fp1   = (unsigned short*)(w + 8 * MB);
    unsigned short* fp2   = (unsigned short*)(w + 16 * MB);
    unsigned short* fp3   = (unsigned short*)(w + 81 * MB);

    static bool lds_inited = false;
    if (!lds_inited) {
        (void)hipFuncSetAttribute((const void*)&gemm256<0, 0>,
                                  hipFuncAttributeMaxDynamicSharedMemorySize, 131072);
        (void)hipFuncSetAttribute((const void*)&gemm256<1, 0>,
                                  hipFuncAttributeMaxDynamicSharedMemorySize, 131072);
        (void)hipFuncSetAttribute((const void*)&gemm256<0, 1>,
                                  hipFuncAttributeMaxDynamicSharedMemorySize, 131072);
        lds_inited = true;
    }

    dim3 blk(256);
    dim3 blk2(512);

    prep<<<dim3(16396), blk, 0, stream>>>(x, Wq, Wk, Wv, bq, bk, bv, Wo, W1, W2,
                                          xb, Wqkvt, Wot, W1t, W2t, bqkv);

    // QKV: M=4096, N=3072 -> 16x12 tiles = 192 blocks
    gemm256<0, 0><<<dim3(192), blk2, 131072, stream>>>(xb, Wqkvt, bqkv,
                                                       qkv, nullptr, nullptr, nullptr,
                                                       M_, 3072, E_);

    v_transpose_perm<<<dim3(L_ / 64, H_, B_), blk, 0, stream>>>(qkv, vtg);

    attn_mfma<<<dim3(512), blk, 0, stream>>>(qkv, vtg, zb);

    // Wo: N=1024 -> 4 n-tiles, split-K=4 -> 256 blocks (KT=4 per plane)
    gemm256<0, 1><<<dim3(256), blk2, 131072, stream>>>(zb, Wot, nullptr,
                                                       ap0, ap1, ap2, ap3,
                                                       M_, E_, E_);

    ln5_kernel<1><<<dim3(M_), blk, 0, stream>>>(x, ap0, ap1, ap2, ap3, bo, g1, beta1, h, hb);

    // FFN1: M=4096, N=4096 -> 16x16 = 256 blocks
    gemm256<1, 0><<<dim3(256), blk2, 131072, stream>>>(hb, W1t, c1,
                                                       ff1b, nullptr, nullptr, nullptr,
                                                       M_, DFF, E_);

    // FFN2: N=1024 -> 4 n-tiles, split-K=4 -> 256 blocks (KT=16 per plane)
    gemm256<0, 1><<<dim3(256), blk2, 131072, stream>>>(ff1b, W2t, nullptr,
                                                       fp0, fp1, fp2, fp3,
                                                       M_, E_, DFF);

    ln5_kernel<0><<<dim3(M_), blk, 0, stream>>>(h, fp0, fp1, fp2, fp3, c2, g2, beta2, out, nullptr);
}

// Round 4
// 338.234 us; speedup vs baseline: 1.1152x; 1.0090x over previous
//
#include <hip/hip_runtime.h>
#include <hip/hip_bf16.h>
#include <math.h>

#define B_   2
#define L_   2048
#define E_   1024
#define H_   16
#define DH   64
#define DFF  4096
#define M_   4096
#define APAD 72
#define SCALE_Q 0.18033688011112042f   // log2(e)/8, folded into Wq/bq

typedef __attribute__((ext_vector_type(8))) short short8;
typedef __attribute__((ext_vector_type(4))) float f32x4;
typedef __bf16 bf16x8 __attribute__((ext_vector_type(8)));

__device__ __forceinline__ float bf2f(unsigned short u) {
    return __uint_as_float(((unsigned)u) << 16);
}
__device__ __forceinline__ unsigned short f2bf(float f) {
    unsigned u = __float_as_uint(f);
    return (unsigned short)((u + 0x7fff + ((u >> 16) & 1)) >> 16);
}
__device__ __forceinline__ unsigned pk_trunc(float lo, float hi) {
    return (__float_as_uint(lo) >> 16) | (__float_as_uint(hi) & 0xffff0000u);
}

// Async global->LDS, 16B/lane. LDS dest = wave-uniform base + lane*16B.
__device__ __forceinline__ void gld16(const unsigned short* g, unsigned short* l) {
    __builtin_amdgcn_global_load_lds(
        (const __attribute__((address_space(1))) void*)g,
        (__attribute__((address_space(3))) void*)l, 16, 0, 0);
}

// ---------------------------------------------------------------------------
// Fused preprocessing (unchanged).
// ---------------------------------------------------------------------------
__global__ __launch_bounds__(256) void prep(const float* __restrict__ x,
                                            const float* __restrict__ Wq,
                                            const float* __restrict__ Wk,
                                            const float* __restrict__ Wv,
                                            const float* __restrict__ bq,
                                            const float* __restrict__ bk,
                                            const float* __restrict__ bv,
                                            const float* __restrict__ Wo,
                                            const float* __restrict__ W1,
                                            const float* __restrict__ W2,
                                            unsigned short* __restrict__ xb,
                                            unsigned short* __restrict__ Wqkvt,
                                            unsigned short* __restrict__ Wot,
                                            unsigned short* __restrict__ W1t,
                                            unsigned short* __restrict__ W2t,
                                            float* __restrict__ bqkv) {
    __shared__ float tile[32][33];
    int bid = blockIdx.x;
    const int t = threadIdx.x;

    if (bid < 4096) {                      // x -> bf16
        int i = (bid * 256 + t) * 4;
        float4 v = *(const float4*)&x[i];
        ushort4 pk = { f2bf(v.x), f2bf(v.y), f2bf(v.z), f2bf(v.w) };
        *(ushort4*)&xb[i] = pk;
        return;
    }
    bid -= 4096;

    const float* in; unsigned short* outp; int R, C, r0, c0; float sc = 1.f;
    if (bid < 3072) {                      // Wqkv: per-head [E][DH] -> [DH][E]
        int xq = bid & 1, yq = (bid >> 1) & 31, wh = bid >> 6;
        int which = wh >> 4, h = wh & 15;
        in   = (which == 0 ? Wq : which == 1 ? Wk : Wv) + (size_t)h * E_ * DH;
        outp = Wqkvt + ((size_t)which * 1024 + h * 64) * 1024;
        R = E_; C = DH; r0 = yq * 32; c0 = xq * 32;
        if (which == 0) sc = SCALE_Q;
    } else if (bid < 4096) {               // Wo [E][E]
        bid -= 3072;
        in = Wo; outp = Wot; R = E_; C = E_;
        c0 = (bid & 31) * 32; r0 = (bid >> 5) * 32;
    } else if (bid < 8192) {               // W1 [E][DFF]
        bid -= 4096;
        in = W1; outp = W1t; R = E_; C = DFF;
        c0 = (bid & 127) * 32; r0 = (bid >> 7) * 32;
    } else if (bid < 12288) {              // W2 [DFF][E]
        bid -= 8192;
        in = W2; outp = W2t; R = DFF; C = E_;
        c0 = (bid & 31) * 32; r0 = (bid >> 5) * 32;
    } else {                               // bqkv
        bid -= 12288;
        int n = bid * 256 + t;
        bqkv[n] = n < 1024 ? bq[n] * SCALE_Q : n < 2048 ? bk[n - 1024] : bv[n - 2048];
        return;
    }

    const int tx = t & 31, tq = t >> 5;
#pragma unroll
    for (int s2 = 0; s2 < 4; s2++)
        tile[tq * 4 + s2][tx] = in[(size_t)(r0 + tq * 4 + s2) * C + c0 + tx] * sc;
    __syncthreads();
#pragma unroll
    for (int s2 = 0; s2 < 4; s2++)
        outp[(size_t)(c0 + tq * 4 + s2) * R + r0 + tx] = f2bf(tile[tx][tq * 4 + s2]);
}

// ---------------------------------------------------------------------------
// V pre-transpose with pi-permuted columns (unchanged).
// ---------------------------------------------------------------------------
__global__ __launch_bounds__(256) void v_transpose_perm(const unsigned short* __restrict__ qkv,
                                                        unsigned short* __restrict__ vtg) {
    __shared__ unsigned short tile[64 * APAD];
    const int t  = threadIdx.x;
    const int kt = blockIdx.x, hh = blockIdx.y, b = blockIdx.z;
    const int rr0 = t >> 3, o8 = (t & 7) * 8, rr1 = rr0 + 32;
    const size_t gbase = ((size_t)b * L_ + kt * 64) * 3072 + 2048 + hh * 64;
    *(short8*)&tile[rr0 * APAD + o8] = *(const short8*)&qkv[gbase + (size_t)rr0 * 3072 + o8];
    *(short8*)&tile[rr1 * APAD + o8] = *(const short8*)&qkv[gbase + (size_t)rr1 * 3072 + o8];
    __syncthreads();
    const size_t obase = ((size_t)(b * H_ + hh) * 64) * (size_t)L_ + kt * 64;
    const int a = t & 15, d0 = (t >> 4) * 4;
#pragma unroll
    for (int s2 = 0; s2 < 4; s2++) {
        int d = d0 + s2;
        ushort4 pk = { tile[(a +  0) * APAD + d], tile[(a + 16) * APAD + d],
                       tile[(a + 32) * APAD + d], tile[(a + 48) * APAD + d] };
        *(ushort4*)&vtg[obase + (size_t)d * L_ + 4 * a] = pk;
    }
}

// ---------------------------------------------------------------------------
// 256x256 8-phase bf16 GEMM (m201 template, plain HIP). Unchanged.
// ---------------------------------------------------------------------------
#define BAR() __builtin_amdgcn_s_barrier()
#define LGKM0() do { asm volatile("s_waitcnt lgkmcnt(0)" ::: "memory"); \
                     __builtin_amdgcn_sched_barrier(0); } while (0)

#define G256_READ_A(qr) do {                                                  \
    _Pragma("unroll") for (int mi = 0; mi < 4; mi++)                          \
    _Pragma("unroll") for (int ks = 0; ks < 2; ks++)                          \
        afr[mi][ks] = *(const bf16x8*)&As[bb + ((qr) * 128 + aRow + mi * 16) * 64 + (ks ? cs1 : cs0)]; \
} while (0)

#define G256_READ_B(qc) do {                                                  \
    _Pragma("unroll") for (int nj = 0; nj < 2; nj++)                          \
    _Pragma("unroll") for (int ks = 0; ks < 2; ks++)                          \
        bfr[qc][nj][ks] = *(const bf16x8*)&Bs[bb + ((qc) * 128 + bRow + nj * 16) * 64 + (ks ? cs1 : cs0)]; \
} while (0)

#define G256_MFMA(qr, qc) do {                                                \
    __builtin_amdgcn_s_setprio(1);                                            \
    _Pragma("unroll") for (int mi = 0; mi < 4; mi++)                          \
    _Pragma("unroll") for (int nj = 0; nj < 2; nj++)                          \
    _Pragma("unroll") for (int ks = 0; ks < 2; ks++)                          \
        acc[qr][qc][mi][nj] = __builtin_amdgcn_mfma_f32_16x16x32_bf16(        \
            afr[mi][ks], bfr[qc][nj][ks], acc[qr][qc][mi][nj], 0, 0, 0);      \
    __builtin_amdgcn_s_setprio(0);                                            \
} while (0)

template <int RELU, int SK>
__global__ __launch_bounds__(512, 2) void gemm256(const unsigned short* __restrict__ A,
                                                  const unsigned short* __restrict__ Bt,
                                                  const float* __restrict__ bias,
                                                  unsigned short* __restrict__ P0,
                                                  unsigned short* __restrict__ P1,
                                                  unsigned short* __restrict__ P2,
                                                  unsigned short* __restrict__ P3,
                                                  int M, int N, int K) {
    extern __shared__ __align__(16) unsigned short g_lds[];
    unsigned short* As = g_lds;            // [2][256][64] elems
    unsigned short* Bs = g_lds + 32768;    // [2][256][64] elems

    const int t    = threadIdx.x;
    const int lane = t & 63;
    const int w    = t >> 6;
    const int quad = lane >> 4;
    const int l16  = lane & 15;

    const int lin = blockIdx.x;
    const int xcd = lin & 7, s = lin >> 3;
    const int m0 = ((xcd << 1) | (s & 1)) * 256;
    const int rest = s >> 1;
    int n0, kbeg, KT;
    unsigned short* C;
    if (SK) {                       // N=1024 -> 4 n-tiles, split-K=4
        n0 = (rest & 3) * 256;
        const int z  = rest >> 2;
        const int K4 = K >> 2;
        kbeg = z * K4;
        KT   = K4 >> 6;
        C = (z == 0) ? P0 : (z == 1) ? P1 : (z == 2) ? P2 : P3;
    } else {
        n0 = rest * 256;
        kbeg = 0;
        KT   = K >> 6;
        C = P0;
    }

    // staging addressing: thread t covers (row = L*64 + (t>>3), slot t&7)
    const int srow = t >> 3;
    const int ksw  = ((t & 7) ^ (srow & 7)) * 8;
    const size_t aStage = (size_t)(m0 + srow) * K + kbeg + ksw;
    const size_t bStage = (size_t)(n0 + srow) * K + kbeg + ksw;

    auto stageA = [&](int buf, int h, int v) {
        size_t g = aStage + (size_t)(h * 128) * K + (size_t)v * 64;
        unsigned short* l = As + buf * 16384 + h * 8192 + w * 512;
        gld16(A + g, l);
        gld16(A + g + (size_t)64 * K, l + 4096);
    };
    auto stageB = [&](int buf, int h, int v) {
        size_t g = bStage + (size_t)(h * 128) * K + (size_t)v * 64;
        unsigned short* l = Bs + buf * 16384 + h * 8192 + w * 512;
        gld16(Bt + g, l);
        gld16(Bt + g + (size_t)64 * K, l + 4096);
    };

    const int aRow = (w >> 2) * 64 + l16;
    const int bRow = (w & 3) * 32 + l16;
    const int cs0  = (quad ^ (l16 & 7)) * 8;
    const int cs1  = cs0 ^ 32;

    f32x4 acc[2][2][4][2];
#pragma unroll
    for (int a1 = 0; a1 < 2; a1++)
#pragma unroll
        for (int a2 = 0; a2 < 2; a2++)
#pragma unroll
            for (int a3 = 0; a3 < 4; a3++)
#pragma unroll
                for (int a4 = 0; a4 < 2; a4++)
                    acc[a1][a2][a3][a4] = (f32x4){0.f, 0.f, 0.f, 0.f};

    bf16x8 afr[4][2], bfr[2][2][2];

    stageA(0, 0, 0); stageA(0, 1, 0); stageB(0, 0, 0); stageB(0, 1, 0);
    if (KT > 1) {
        stageA(1, 0, 1); stageB(1, 0, 1);
        asm volatile("s_waitcnt vmcnt(4)" ::: "memory");
    } else {
        asm volatile("s_waitcnt vmcnt(0)" ::: "memory");
    }
    BAR();

    for (int u = 0; u < KT; ++u) {
        const int bb = (u & 1) * 16384;
        const int nb = ((u + 1) & 1);

        // ---- P1 (0,0)
        G256_READ_A(0);
        G256_READ_B(0);
        if (u + 1 < KT) stageB(nb, 1, u + 1);        // B1(u+1)
        BAR(); LGKM0();
        G256_MFMA(0, 0);
        BAR();

        // ---- P2 (0,1)
        G256_READ_B(1);
        if (u + 1 < KT) stageA(nb, 1, u + 1);        // A1(u+1)
        BAR(); LGKM0();
        G256_MFMA(0, 1);
        BAR();

        // ---- P3 (1,0)
        G256_READ_A(1);
        if (u + 2 < KT) stageA(u & 1, 0, u + 2);     // A0(u+2)
        BAR(); LGKM0();
        G256_MFMA(1, 0);
        BAR();

        // ---- P4 (1,1)
        if (u + 2 < KT) {
            stageB(u & 1, 0, u + 2);                 // B0(u+2)
            asm volatile("s_waitcnt vmcnt(4)" ::: "memory");
        } else {
            asm volatile("s_waitcnt vmcnt(0)" ::: "memory");
        }
        BAR(); LGKM0();
        G256_MFMA(1, 1);
        BAR();
    }

#pragma unroll
    for (int qr = 0; qr < 2; qr++)
#pragma unroll
        for (int qc = 0; qc < 2; qc++)
#pragma unroll
            for (int nj = 0; nj < 2; nj++) {
                const int col = n0 + qc * 128 + (w & 3) * 32 + nj * 16 + l16;
                const float bv = SK ? 0.f : bias[col];
#pragma unroll
                for (int mi = 0; mi < 4; mi++) {
                    const int row = m0 + qr * 128 + (w >> 2) * 64 + mi * 16 + quad * 4;
#pragma unroll
                    for (int r = 0; r < 4; r++) {
                        float v = acc[qr][qc][mi][nj][r] + bv;
                        if (RELU) v = fmaxf(v, 0.f);
                        C[(size_t)(row + r) * N + col] = f2bf(v);
                    }
                }
            }
}

// ---------------------------------------------------------------------------
// MFMA flash attention v6: 8 waves x 16 q-rows (512 threads), QBLK=128.
// Same grid (512 blocks) and LDS (46 KB) as v5, but 16 waves/CU instead of 8
// -> latency hiding across the serial QK->softmax->PV chain via the second
// resident block. K/V staged with one short8 per thread (512 thr = 64x64).
// ---------------------------------------------------------------------------
__global__ __launch_bounds__(512, 4) void attn_mfma(const unsigned short* __restrict__ qkv,
                                                    const unsigned short* __restrict__ vtg,
                                                    unsigned short* __restrict__ zb) {
    __shared__ __align__(16) unsigned short ks[2][64 * APAD];
    __shared__ __align__(16) unsigned short vt[64 * APAD];
    __shared__ __align__(16) unsigned short ps[128 * APAD];

    const int t    = threadIdx.x;
    const int lane = t & 63;
    const int w    = t >> 6;          // 0..7, each wave owns 16 q-rows
    const int l16  = lane & 15;
    const int quad = lane >> 4;

    const int lin  = blockIdx.x;
    const int xcd  = lin & 7;
    const int s    = lin >> 3;
    const int hh   = xcd * 2 + (s & 1);
    const int rest = s >> 1;
    const int b    = rest & 1;
    const int qq0  = rest >> 1;
    const int qq   = b ? qq0 : 15 - qq0;

    const size_t rowbase = (size_t)b * L_;
    const size_t vbase   = ((size_t)(b * H_ + hh) * 64) * (size_t)L_;

    // Q fragment: wave w covers rows qq*128 + w*16 .. +15
    bf16x8 qf[2];
    {
        size_t qrow = rowbase + qq * 128 + w * 16 + l16;
#pragma unroll
        for (int c = 0; c < 2; c++)
            qf[c] = *(const bf16x8*)&qkv[qrow * 3072 + hh * 64 + c * 32 + quad * 8];
    }

    f32x4 o[4];
#pragma unroll
    for (int j = 0; j < 4; j++) o[j] = (f32x4){0.f, 0.f, 0.f, 0.f};
    float l_i[4] = {};

    const int rr = t >> 3, o8 = (t & 7) * 8;   // 512 threads cover 64 rows x 64 cols
    const int ktmax = 2 * qq + 1;

    {   // preload tile 0
        size_t kg = rowbase * 3072 + 1024 + hh * 64;
        short8 k0 = *(const short8*)&qkv[kg + (size_t)rr * 3072 + o8];
        short8 v0 = *(const short8*)&vtg[vbase + (size_t)rr * L_ + o8];
        *(short8*)&ks[0][rr * APAD + o8] = k0;
        *(short8*)&vt[rr * APAD + o8] = v0;
    }

    short8 kr0, vr0;
    for (int kt = 0; kt <= ktmax; kt++) {
        const int p = kt & 1;
        __syncthreads();

        if (kt < ktmax) {
            size_t kg = (rowbase + (kt + 1) * 64) * 3072 + 1024 + hh * 64;
            kr0 = *(const short8*)&qkv[kg + (size_t)rr * 3072 + o8];
            vr0 = *(const short8*)&vtg[vbase + (kt + 1) * 64 + (size_t)rr * L_ + o8];
        }

        f32x4 s4[4];
#pragma unroll
        for (int j = 0; j < 4; j++) s4[j] = (f32x4){0.f, 0.f, 0.f, 0.f};
#pragma unroll
        for (int c = 0; c < 2; c++)
#pragma unroll
            for (int j = 0; j < 4; j++) {
                bf16x8 kf = *(const bf16x8*)&ks[p][(j * 16 + l16) * APAD + c * 32 + quad * 8];
                s4[j] = __builtin_amdgcn_mfma_f32_16x16x32_bf16(qf[c], kf, s4[j], 0, 0, 0);
            }

        if (kt >= 2 * qq) {
#pragma unroll
            for (int j = 0; j < 4; j++) {
                int lk = kt * 64 + j * 16 + l16;
#pragma unroll
                for (int r = 0; r < 4; r++)
                    if (lk > qq * 128 + w * 16 + quad * 4 + r)
                        s4[j][r] = -INFINITY;
            }
        }

#pragma unroll
        for (int r = 0; r < 4; r++) {
            float p0 = __builtin_amdgcn_exp2f(s4[0][r]);
            float p1 = __builtin_amdgcn_exp2f(s4[1][r]);
            float p2 = __builtin_amdgcn_exp2f(s4[2][r]);
            float p3 = __builtin_amdgcn_exp2f(s4[3][r]);
            l_i[r] += (p0 + p1) + (p2 + p3);
            uint2 pk = { pk_trunc(p0, p1), pk_trunc(p2, p3) };
            *(uint2*)&ps[(w * 16 + quad * 4 + r) * APAD + 4 * l16] = pk;
        }

        __builtin_amdgcn_s_waitcnt(0xc07f);   // lgkmcnt(0): own-row P writes visible

#pragma unroll
        for (int c = 0; c < 2; c++) {
            bf16x8 pf = *(const bf16x8*)&ps[(w * 16 + l16) * APAD + c * 32 + quad * 8];
#pragma unroll
            for (int j = 0; j < 4; j++) {
                bf16x8 vf = *(const bf16x8*)&vt[(j * 16 + l16) * APAD + c * 32 + quad * 8];
                o[j] = __builtin_amdgcn_mfma_f32_16x16x32_bf16(pf, vf, o[j], 0, 0, 0);
            }
        }

        __syncthreads();
        if (kt < ktmax) {
            *(short8*)&ks[p ^ 1][rr * APAD + o8] = kr0;
            *(short8*)&vt[rr * APAD + o8] = vr0;
        }
    }

#pragma unroll
    for (int r = 0; r < 4; r++) {
        float l = l_i[r];
        l += __shfl_xor(l, 1);
        l += __shfl_xor(l, 2);
        l += __shfl_xor(l, 4);
        l += __shfl_xor(l, 8);
        float inv = 1.f / l;
        size_t row = rowbase + qq * 128 + w * 16 + quad * 4 + r;
#pragma unroll
        for (int j = 0; j < 4; j++)
            zb[row * 1024 + hh * 64 + j * 16 + l16] = f2bf(o[j][r] * inv);
    }
}

// ---------------------------------------------------------------------------
// LayerNorm(a + sum of 4 bf16 partial planes + bias) * g + beta.
// ---------------------------------------------------------------------------
template <int WRITE_BF16>
__global__ __launch_bounds__(256) void ln5_kernel(const float* __restrict__ a,
                                                  const unsigned short* __restrict__ q0,
                                                  const unsigned short* __restrict__ q1,
                                                  const unsigned short* __restrict__ q2,
                                                  const unsigned short* __restrict__ q3,
                                                  const float* __restrict__ bias,
                                                  const float* __restrict__ g,
                                                  const float* __restrict__ be,
                                                  float* __restrict__ out,
                                                  unsigned short* __restrict__ out_bf) {
    __shared__ float s1[256], s2[256];
    const int row = blockIdx.x;
    const int t   = threadIdx.x;
    const size_t base = (size_t)row * E_ + t * 4;

    float4 ya = *(const float4*)&a[base];
    ushort4 u0 = *(const ushort4*)&q0[base];
    ushort4 u1 = *(const ushort4*)&q1[base];
    ushort4 u2 = *(const ushort4*)&q2[base];
    ushort4 u3 = *(const ushort4*)&q3[base];
    float4 bb = *(const float4*)&bias[t * 4];
    float y0 = ya.x + bb.x + bf2f(u0.x) + bf2f(u1.x) + bf2f(u2.x) + bf2f(u3.x);
    float y1 = ya.y + bb.y + bf2f(u0.y) + bf2f(u1.y) + bf2f(u2.y) + bf2f(u3.y);
    float y2 = ya.z + bb.z + bf2f(u0.z) + bf2f(u1.z) + bf2f(u2.z) + bf2f(u3.z);
    float y3 = ya.w + bb.w + bf2f(u0.w) + bf2f(u1.w) + bf2f(u2.w) + bf2f(u3.w);

    s1[t] = y0 + y1 + y2 + y3;
    s2[t] = y0 * y0 + y1 * y1 + y2 * y2 + y3 * y3;
    __syncthreads();
    for (int off = 128; off > 0; off >>= 1) {
        if (t < off) { s1[t] += s1[t + off]; s2[t] += s2[t + off]; }
        __syncthreads();
    }
    float mean = s1[0] * (1.0f / E_);
    float var  = s2[0] * (1.0f / E_) - mean * mean;
    float rstd = rsqrtf(var + 1e-5f);

    float4 gv = *(const float4*)&g[t * 4];
    float4 bv = *(const float4*)&be[t * 4];
    float4 ov;
    ov.x = (y0 - mean) * rstd * gv.x + bv.x;
    ov.y = (y1 - mean) * rstd * gv.y + bv.y;
    ov.z = (y2 - mean) * rstd * gv.z + bv.z;
    ov.w = (y3 - mean) * rstd * gv.w + bv.w;
    *(float4*)&out[base] = ov;
    if (WRITE_BF16) {
        ushort4 pk = { f2bf(ov.x), f2bf(ov.y), f2bf(ov.z), f2bf(ov.w) };
        *(ushort4*)&out_bf[base] = pk;
    }
}

// ---------------------------------------------------------------------------
extern "C" void kernel_launch(void* const* d_in, const int* in_sizes, int n_in,
                              void* d_out, int out_size, void* d_ws, size_t ws_size,
                              hipStream_t stream)
{
    const float* x     = (const float*)d_in[0];
    const float* Wq    = (const float*)d_in[2];
    const float* bq    = (const float*)d_in[3];
    const float* Wk    = (const float*)d_in[4];
    const float* bk    = (const float*)d_in[5];
    const float* Wv    = (const float*)d_in[6];
    const float* bv    = (const float*)d_in[7];
    const float* Wo    = (const float*)d_in[8];
    const float* bo    = (const float*)d_in[9];
    const float* W1    = (const float*)d_in[10];
    const float* c1    = (const float*)d_in[11];
    const float* W2    = (const float*)d_in[12];
    const float* c2    = (const float*)d_in[13];
    const float* g1    = (const float*)d_in[14];
    const float* beta1 = (const float*)d_in[15];
    const float* g2    = (const float*)d_in[16];
    const float* beta2 = (const float*)d_in[17];
    float* out = (float*)d_out;

    const size_t MB = 1024 * 1024;
    char* w = (char*)d_ws;
    unsigned short* xb    = (unsigned short*)(w + 0 * MB);    // [0,8)   prep..QKV
    unsigned short* Wqkvt = (unsigned short*)(w + 8 * MB);    // [8,14)
    unsigned short* Wot   = (unsigned short*)(w + 14 * MB);   // [14,16)
    unsigned short* W1t   = (unsigned short*)(w + 16 * MB);   // [16,24)
    unsigned short* W2t   = (unsigned short*)(w + 24 * MB);   // [24,32)
    float*          bqkv  = (float*)(w + 32 * MB);            // [32,33)
    unsigned short* qkv   = (unsigned short*)(w + 33 * MB);   // [33,57)  QKV..attn
    unsigned short* zb    = (unsigned short*)(w + 57 * MB);   // [57,65)  attn..Wo
    float*          h     = (float*)(w + 65 * MB);            // [65,81)  LN1..LN2
    unsigned short* vtg   = (unsigned short*)(w + 89 * MB);   // [89,97)  vT..attn
    // Wo partials (bf16, 8 MB each): over dead qkv + dead vtg
    unsigned short* ap0   = (unsigned short*)(w + 33 * MB);
    unsigned short* ap1   = (unsigned short*)(w + 41 * MB);
    unsigned short* ap2   = (unsigned short*)(w + 49 * MB);
    unsigned short* ap3   = (unsigned short*)(w + 89 * MB);
    unsigned short* hb    = (unsigned short*)(w + 0 * MB);    // LN1..FFN1 (over xb)
    unsigned short* ff1b  = (unsigned short*)(w + 33 * MB);   // FFN1..FFN2 [33,65)
    // FFN2 partials (bf16): over dead hb/Wqkvt/Wot/W1t + tail
    unsigned short* fp0   = (unsigned short*)(w + 0 * MB);
    unsigned short* fp1   = (unsigned short*)(w + 8 * MB);
    unsigned short* fp2   = (unsigned short*)(w + 16 * MB);
    unsigned short* fp3   = (unsigned short*)(w + 81 * MB);

    static bool lds_inited = false;
    if (!lds_inited) {
        (void)hipFuncSetAttribute((const void*)&gemm256<0, 0>,
                                  hipFuncAttributeMaxDynamicSharedMemorySize, 131072);
        (void)hipFuncSetAttribute((const void*)&gemm256<1, 0>,
                                  hipFuncAttributeMaxDynamicSharedMemorySize, 131072);
        (void)hipFuncSetAttribute((const void*)&gemm256<0, 1>,
                                  hipFuncAttributeMaxDynamicSharedMemorySize, 131072);
        lds_inited = true;
    }

    dim3 blk(256);
    dim3 blk2(512);

    prep<<<dim3(16396), blk, 0, stream>>>(x, Wq, Wk, Wv, bq, bk, bv, Wo, W1, W2,
                                          xb, Wqkvt, Wot, W1t, W2t, bqkv);

    // QKV: M=4096, N=3072 -> 16x12 tiles = 192 blocks
    gemm256<0, 0><<<dim3(192), blk2, 131072, stream>>>(xb, Wqkvt, bqkv,
                                                       qkv, nullptr, nullptr, nullptr,
                                                       M_, 3072, E_);

    v_transpose_perm<<<dim3(L_ / 64, H_, B_), blk, 0, stream>>>(qkv, vtg);

    attn_mfma<<<dim3(512), blk2, 0, stream>>>(qkv, vtg, zb);

    // Wo: N=1024 -> 4 n-tiles, split-K=4 -> 256 blocks (KT=4 per plane)
    gemm256<0, 1><<<dim3(256), blk2, 131072, stream>>>(zb, Wot, nullptr,
                                                       ap0, ap1, ap2, ap3,
                                                       M_, E_, E_);

    ln5_kernel<1><<<dim3(M_), blk, 0, stream>>>(x, ap0, ap1, ap2, ap3, bo, g1, beta1, h, hb);

    // FFN1: M=4096, N=4096 -> 16x16 = 256 blocks
    gemm256<1, 0><<<dim3(256), blk2, 131072, stream>>>(hb, W1t, c1,
                                                       ff1b, nullptr, nullptr, nullptr,
                                                       M_, DFF, E_);

    // FFN2: N=1024 -> 4 n-tiles, split-K=4 -> 256 blocks (KT=16 per plane)
    gemm256<0, 1><<<dim3(256), blk2, 131072, stream>>>(ff1b, W2t, nullptr,
                                                       fp0, fp1, fp2, fp3,
                                                       M_, E_, DFF);

    ln5_kernel<0><<<dim3(M_), blk, 0, stream>>>(h, fp0, fp1, fp2, fp3, c2, g2, beta2, out, nullptr);
}

// Round 5
// 337.635 us; speedup vs baseline: 1.1172x; 1.0018x over previous
//
#include <hip/hip_runtime.h>
#include <hip/hip_bf16.h>
#include <math.h>

#define B_   2
#define L_   2048
#define E_   1024
#define H_   16
#define DH   64
#define DFF  4096
#define M_   4096
#define APAD 72
#define SCALE_Q 0.18033688011112042f   // log2(e)/8, folded into Wq/bq

typedef __attribute__((ext_vector_type(8))) short short8;
typedef __attribute__((ext_vector_type(4))) float f32x4;
typedef __bf16 bf16x8 __attribute__((ext_vector_type(8)));

__device__ __forceinline__ float bf2f(unsigned short u) {
    return __uint_as_float(((unsigned)u) << 16);
}
__device__ __forceinline__ unsigned short f2bf(float f) {
    unsigned u = __float_as_uint(f);
    return (unsigned short)((u + 0x7fff + ((u >> 16) & 1)) >> 16);
}
__device__ __forceinline__ unsigned pk_trunc(float lo, float hi) {
    return (__float_as_uint(lo) >> 16) | (__float_as_uint(hi) & 0xffff0000u);
}

// Async global->LDS, 16B/lane. LDS dest = wave-uniform base + lane*16B.
__device__ __forceinline__ void gld16(const unsigned short* g, unsigned short* l) {
    __builtin_amdgcn_global_load_lds(
        (const __attribute__((address_space(1))) void*)g,
        (__attribute__((address_space(3))) void*)l, 16, 0, 0);
}

// ---------------------------------------------------------------------------
// Fused preprocessing (unchanged).
// ---------------------------------------------------------------------------
__global__ __launch_bounds__(256) void prep(const float* __restrict__ x,
                                            const float* __restrict__ Wq,
                                            const float* __restrict__ Wk,
                                            const float* __restrict__ Wv,
                                            const float* __restrict__ bq,
                                            const float* __restrict__ bk,
                                            const float* __restrict__ bv,
                                            const float* __restrict__ Wo,
                                            const float* __restrict__ W1,
                                            const float* __restrict__ W2,
                                            unsigned short* __restrict__ xb,
                                            unsigned short* __restrict__ Wqkvt,
                                            unsigned short* __restrict__ Wot,
                                            unsigned short* __restrict__ W1t,
                                            unsigned short* __restrict__ W2t,
                                            float* __restrict__ bqkv) {
    __shared__ float tile[32][33];
    int bid = blockIdx.x;
    const int t = threadIdx.x;

    if (bid < 4096) {                      // x -> bf16
        int i = (bid * 256 + t) * 4;
        float4 v = *(const float4*)&x[i];
        ushort4 pk = { f2bf(v.x), f2bf(v.y), f2bf(v.z), f2bf(v.w) };
        *(ushort4*)&xb[i] = pk;
        return;
    }
    bid -= 4096;

    const float* in; unsigned short* outp; int R, C, r0, c0; float sc = 1.f;
    if (bid < 3072) {                      // Wqkv: per-head [E][DH] -> [DH][E]
        int xq = bid & 1, yq = (bid >> 1) & 31, wh = bid >> 6;
        int which = wh >> 4, h = wh & 15;
        in   = (which == 0 ? Wq : which == 1 ? Wk : Wv) + (size_t)h * E_ * DH;
        outp = Wqkvt + ((size_t)which * 1024 + h * 64) * 1024;
        R = E_; C = DH; r0 = yq * 32; c0 = xq * 32;
        if (which == 0) sc = SCALE_Q;
    } else if (bid < 4096) {               // Wo [E][E]
        bid -= 3072;
        in = Wo; outp = Wot; R = E_; C = E_;
        c0 = (bid & 31) * 32; r0 = (bid >> 5) * 32;
    } else if (bid < 8192) {               // W1 [E][DFF]
        bid -= 4096;
        in = W1; outp = W1t; R = E_; C = DFF;
        c0 = (bid & 127) * 32; r0 = (bid >> 7) * 32;
    } else if (bid < 12288) {              // W2 [DFF][E]
        bid -= 8192;
        in = W2; outp = W2t; R = DFF; C = E_;
        c0 = (bid & 31) * 32; r0 = (bid >> 5) * 32;
    } else {                               // bqkv
        bid -= 12288;
        int n = bid * 256 + t;
        bqkv[n] = n < 1024 ? bq[n] * SCALE_Q : n < 2048 ? bk[n - 1024] : bv[n - 2048];
        return;
    }

    const int tx = t & 31, tq = t >> 5;
#pragma unroll
    for (int s2 = 0; s2 < 4; s2++)
        tile[tq * 4 + s2][tx] = in[(size_t)(r0 + tq * 4 + s2) * C + c0 + tx] * sc;
    __syncthreads();
#pragma unroll
    for (int s2 = 0; s2 < 4; s2++)
        outp[(size_t)(c0 + tq * 4 + s2) * R + r0 + tx] = f2bf(tile[tx][tq * 4 + s2]);
}

// ---------------------------------------------------------------------------
// V pre-transpose with pi-permuted columns (unchanged).
// ---------------------------------------------------------------------------
__global__ __launch_bounds__(256) void v_transpose_perm(const unsigned short* __restrict__ qkv,
                                                        unsigned short* __restrict__ vtg) {
    __shared__ unsigned short tile[64 * APAD];
    const int t  = threadIdx.x;
    const int kt = blockIdx.x, hh = blockIdx.y, b = blockIdx.z;
    const int rr0 = t >> 3, o8 = (t & 7) * 8, rr1 = rr0 + 32;
    const size_t gbase = ((size_t)b * L_ + kt * 64) * 3072 + 2048 + hh * 64;
    *(short8*)&tile[rr0 * APAD + o8] = *(const short8*)&qkv[gbase + (size_t)rr0 * 3072 + o8];
    *(short8*)&tile[rr1 * APAD + o8] = *(const short8*)&qkv[gbase + (size_t)rr1 * 3072 + o8];
    __syncthreads();
    const size_t obase = ((size_t)(b * H_ + hh) * 64) * (size_t)L_ + kt * 64;
    const int a = t & 15, d0 = (t >> 4) * 4;
#pragma unroll
    for (int s2 = 0; s2 < 4; s2++) {
        int d = d0 + s2;
        ushort4 pk = { tile[(a +  0) * APAD + d], tile[(a + 16) * APAD + d],
                       tile[(a + 32) * APAD + d], tile[(a + 48) * APAD + d] };
        *(ushort4*)&vtg[obase + (size_t)d * L_ + 4 * a] = pk;
    }
}

// ---------------------------------------------------------------------------
// 256x256 8-phase bf16 GEMM (m201 template, plain HIP). Unchanged.
// ---------------------------------------------------------------------------
#define BAR() __builtin_amdgcn_s_barrier()
#define LGKM0() do { asm volatile("s_waitcnt lgkmcnt(0)" ::: "memory"); \
                     __builtin_amdgcn_sched_barrier(0); } while (0)

#define G256_READ_A(qr) do {                                                  \
    _Pragma("unroll") for (int mi = 0; mi < 4; mi++)                          \
    _Pragma("unroll") for (int ks = 0; ks < 2; ks++)                          \
        afr[mi][ks] = *(const bf16x8*)&As[bb + ((qr) * 128 + aRow + mi * 16) * 64 + (ks ? cs1 : cs0)]; \
} while (0)

#define G256_READ_B(qc) do {                                                  \
    _Pragma("unroll") for (int nj = 0; nj < 2; nj++)                          \
    _Pragma("unroll") for (int ks = 0; ks < 2; ks++)                          \
        bfr[qc][nj][ks] = *(const bf16x8*)&Bs[bb + ((qc) * 128 + bRow + nj * 16) * 64 + (ks ? cs1 : cs0)]; \
} while (0)

#define G256_MFMA(qr, qc) do {                                                \
    __builtin_amdgcn_s_setprio(1);                                            \
    _Pragma("unroll") for (int mi = 0; mi < 4; mi++)                          \
    _Pragma("unroll") for (int nj = 0; nj < 2; nj++)                          \
    _Pragma("unroll") for (int ks = 0; ks < 2; ks++)                          \
        acc[qr][qc][mi][nj] = __builtin_amdgcn_mfma_f32_16x16x32_bf16(        \
            afr[mi][ks], bfr[qc][nj][ks], acc[qr][qc][mi][nj], 0, 0, 0);      \
    __builtin_amdgcn_s_setprio(0);                                            \
} while (0)

template <int RELU, int SK>
__global__ __launch_bounds__(512, 2) void gemm256(const unsigned short* __restrict__ A,
                                                  const unsigned short* __restrict__ Bt,
                                                  const float* __restrict__ bias,
                                                  unsigned short* __restrict__ P0,
                                                  unsigned short* __restrict__ P1,
                                                  unsigned short* __restrict__ P2,
                                                  unsigned short* __restrict__ P3,
                                                  int M, int N, int K) {
    extern __shared__ __align__(16) unsigned short g_lds[];
    unsigned short* As = g_lds;            // [2][256][64] elems
    unsigned short* Bs = g_lds + 32768;    // [2][256][64] elems

    const int t    = threadIdx.x;
    const int lane = t & 63;
    const int w    = t >> 6;
    const int quad = lane >> 4;
    const int l16  = lane & 15;

    const int lin = blockIdx.x;
    const int xcd = lin & 7, s = lin >> 3;
    const int m0 = ((xcd << 1) | (s & 1)) * 256;
    const int rest = s >> 1;
    int n0, kbeg, KT;
    unsigned short* C;
    if (SK) {                       // N=1024 -> 4 n-tiles, split-K=4
        n0 = (rest & 3) * 256;
        const int z  = rest >> 2;
        const int K4 = K >> 2;
        kbeg = z * K4;
        KT   = K4 >> 6;
        C = (z == 0) ? P0 : (z == 1) ? P1 : (z == 2) ? P2 : P3;
    } else {
        n0 = rest * 256;
        kbeg = 0;
        KT   = K >> 6;
        C = P0;
    }

    // staging addressing: thread t covers (row = L*64 + (t>>3), slot t&7)
    const int srow = t >> 3;
    const int ksw  = ((t & 7) ^ (srow & 7)) * 8;
    const size_t aStage = (size_t)(m0 + srow) * K + kbeg + ksw;
    const size_t bStage = (size_t)(n0 + srow) * K + kbeg + ksw;

    auto stageA = [&](int buf, int h, int v) {
        size_t g = aStage + (size_t)(h * 128) * K + (size_t)v * 64;
        unsigned short* l = As + buf * 16384 + h * 8192 + w * 512;
        gld16(A + g, l);
        gld16(A + g + (size_t)64 * K, l + 4096);
    };
    auto stageB = [&](int buf, int h, int v) {
        size_t g = bStage + (size_t)(h * 128) * K + (size_t)v * 64;
        unsigned short* l = Bs + buf * 16384 + h * 8192 + w * 512;
        gld16(Bt + g, l);
        gld16(Bt + g + (size_t)64 * K, l + 4096);
    };

    const int aRow = (w >> 2) * 64 + l16;
    const int bRow = (w & 3) * 32 + l16;
    const int cs0  = (quad ^ (l16 & 7)) * 8;
    const int cs1  = cs0 ^ 32;

    f32x4 acc[2][2][4][2];
#pragma unroll
    for (int a1 = 0; a1 < 2; a1++)
#pragma unroll
        for (int a2 = 0; a2 < 2; a2++)
#pragma unroll
            for (int a3 = 0; a3 < 4; a3++)
#pragma unroll
                for (int a4 = 0; a4 < 2; a4++)
                    acc[a1][a2][a3][a4] = (f32x4){0.f, 0.f, 0.f, 0.f};

    bf16x8 afr[4][2], bfr[2][2][2];

    stageA(0, 0, 0); stageA(0, 1, 0); stageB(0, 0, 0); stageB(0, 1, 0);
    if (KT > 1) {
        stageA(1, 0, 1); stageB(1, 0, 1);
        asm volatile("s_waitcnt vmcnt(4)" ::: "memory");
    } else {
        asm volatile("s_waitcnt vmcnt(0)" ::: "memory");
    }
    BAR();

    for (int u = 0; u < KT; ++u) {
        const int bb = (u & 1) * 16384;
        const int nb = ((u + 1) & 1);

        // ---- P1 (0,0)
        G256_READ_A(0);
        G256_READ_B(0);
        if (u + 1 < KT) stageB(nb, 1, u + 1);        // B1(u+1)
        BAR(); LGKM0();
        G256_MFMA(0, 0);
        BAR();

        // ---- P2 (0,1)
        G256_READ_B(1);
        if (u + 1 < KT) stageA(nb, 1, u + 1);        // A1(u+1)
        BAR(); LGKM0();
        G256_MFMA(0, 1);
        BAR();

        // ---- P3 (1,0)
        G256_READ_A(1);
        if (u + 2 < KT) stageA(u & 1, 0, u + 2);     // A0(u+2)
        BAR(); LGKM0();
        G256_MFMA(1, 0);
        BAR();

        // ---- P4 (1,1)
        if (u + 2 < KT) {
            stageB(u & 1, 0, u + 2);                 // B0(u+2)
            asm volatile("s_waitcnt vmcnt(4)" ::: "memory");
        } else {
            asm volatile("s_waitcnt vmcnt(0)" ::: "memory");
        }
        BAR(); LGKM0();
        G256_MFMA(1, 1);
        BAR();
    }

#pragma unroll
    for (int qr = 0; qr < 2; qr++)
#pragma unroll
        for (int qc = 0; qc < 2; qc++)
#pragma unroll
            for (int nj = 0; nj < 2; nj++) {
                const int col = n0 + qc * 128 + (w & 3) * 32 + nj * 16 + l16;
                const float bv = SK ? 0.f : bias[col];
#pragma unroll
                for (int mi = 0; mi < 4; mi++) {
                    const int row = m0 + qr * 128 + (w >> 2) * 64 + mi * 16 + quad * 4;
#pragma unroll
                    for (int r = 0; r < 4; r++) {
                        float v = acc[qr][qc][mi][nj][r] + bv;
                        if (RELU) v = fmaxf(v, 0.f);
                        C[(size_t)(row + r) * N + col] = f2bf(v);
                    }
                }
            }
}

// ---------------------------------------------------------------------------
// MFMA flash attention v7: 8 waves x 16 q-rows, one block processes the
// causal-complementary q-tile PAIR (qq, 15-qq) sequentially -> every block
// does exactly 34 K-tiles (uniform work, zero tail). Grid = B*H*8 = 256
// blocks = exactly 1/CU. setprio(1) around MFMA clusters (T5).
// ---------------------------------------------------------------------------
__global__ __launch_bounds__(512, 4) void attn_mfma(const unsigned short* __restrict__ qkv,
                                                    const unsigned short* __restrict__ vtg,
                                                    unsigned short* __restrict__ zb) {
    __shared__ __align__(16) unsigned short ks[2][64 * APAD];
    __shared__ __align__(16) unsigned short vt[64 * APAD];
    __shared__ __align__(16) unsigned short ps[128 * APAD];

    const int t    = threadIdx.x;
    const int lane = t & 63;
    const int w    = t >> 6;          // 0..7, each wave owns 16 q-rows
    const int l16  = lane & 15;
    const int quad = lane >> 4;

    const int lin  = blockIdx.x;      // 256 blocks
    const int xcd  = lin & 7;
    const int s    = lin >> 3;
    const int hh   = xcd * 2 + (s & 1);
    const int rest = s >> 1;          // 0..15
    const int b    = rest & 1;
    const int pair = rest >> 1;       // 0..7

    const size_t rowbase = (size_t)b * L_;
    const size_t vbase   = ((size_t)(b * H_ + hh) * 64) * (size_t)L_;
    const int rr = t >> 3, o8 = (t & 7) * 8;   // 512 threads cover 64x64 tile

    for (int ph = 0; ph < 2; ph++) {
        const int qq = ph ? pair : 15 - pair;

        // Q fragment: wave w covers rows qq*128 + w*16 .. +15
        bf16x8 qf[2];
        {
            size_t qrow = rowbase + qq * 128 + w * 16 + l16;
#pragma unroll
            for (int c = 0; c < 2; c++)
                qf[c] = *(const bf16x8*)&qkv[qrow * 3072 + hh * 64 + c * 32 + quad * 8];
        }

        f32x4 o[4];
#pragma unroll
        for (int j = 0; j < 4; j++) o[j] = (f32x4){0.f, 0.f, 0.f, 0.f};
        float l_i[4] = {};

        const int ktmax = 2 * qq + 1;

        {   // preload tile 0 (prior phase's last PV reads were barrier'd)
            size_t kg = rowbase * 3072 + 1024 + hh * 64;
            short8 k0 = *(const short8*)&qkv[kg + (size_t)rr * 3072 + o8];
            short8 v0 = *(const short8*)&vtg[vbase + (size_t)rr * L_ + o8];
            *(short8*)&ks[0][rr * APAD + o8] = k0;
            *(short8*)&vt[rr * APAD + o8] = v0;
        }

        short8 kr0, vr0;
        for (int kt = 0; kt <= ktmax; kt++) {
            const int p = kt & 1;
            __syncthreads();

            if (kt < ktmax) {
                size_t kg = (rowbase + (kt + 1) * 64) * 3072 + 1024 + hh * 64;
                kr0 = *(const short8*)&qkv[kg + (size_t)rr * 3072 + o8];
                vr0 = *(const short8*)&vtg[vbase + (kt + 1) * 64 + (size_t)rr * L_ + o8];
            }

            f32x4 s4[4];
#pragma unroll
            for (int j = 0; j < 4; j++) s4[j] = (f32x4){0.f, 0.f, 0.f, 0.f};
            __builtin_amdgcn_s_setprio(1);
#pragma unroll
            for (int c = 0; c < 2; c++)
#pragma unroll
                for (int j = 0; j < 4; j++) {
                    bf16x8 kf = *(const bf16x8*)&ks[p][(j * 16 + l16) * APAD + c * 32 + quad * 8];
                    s4[j] = __builtin_amdgcn_mfma_f32_16x16x32_bf16(qf[c], kf, s4[j], 0, 0, 0);
                }
            __builtin_amdgcn_s_setprio(0);

            if (kt >= 2 * qq) {
#pragma unroll
                for (int j = 0; j < 4; j++) {
                    int lk = kt * 64 + j * 16 + l16;
#pragma unroll
                    for (int r = 0; r < 4; r++)
                        if (lk > qq * 128 + w * 16 + quad * 4 + r)
                            s4[j][r] = -INFINITY;
                }
            }

#pragma unroll
            for (int r = 0; r < 4; r++) {
                float p0 = __builtin_amdgcn_exp2f(s4[0][r]);
                float p1 = __builtin_amdgcn_exp2f(s4[1][r]);
                float p2 = __builtin_amdgcn_exp2f(s4[2][r]);
                float p3 = __builtin_amdgcn_exp2f(s4[3][r]);
                l_i[r] += (p0 + p1) + (p2 + p3);
                uint2 pk = { pk_trunc(p0, p1), pk_trunc(p2, p3) };
                *(uint2*)&ps[(w * 16 + quad * 4 + r) * APAD + 4 * l16] = pk;
            }

            __builtin_amdgcn_s_waitcnt(0xc07f);   // lgkmcnt(0): own-row P writes visible

            __builtin_amdgcn_s_setprio(1);
#pragma unroll
            for (int c = 0; c < 2; c++) {
                bf16x8 pf = *(const bf16x8*)&ps[(w * 16 + l16) * APAD + c * 32 + quad * 8];
#pragma unroll
                for (int j = 0; j < 4; j++) {
                    bf16x8 vf = *(const bf16x8*)&vt[(j * 16 + l16) * APAD + c * 32 + quad * 8];
                    o[j] = __builtin_amdgcn_mfma_f32_16x16x32_bf16(pf, vf, o[j], 0, 0, 0);
                }
            }
            __builtin_amdgcn_s_setprio(0);

            __syncthreads();
            if (kt < ktmax) {
                *(short8*)&ks[p ^ 1][rr * APAD + o8] = kr0;
                *(short8*)&vt[rr * APAD + o8] = vr0;
            }
        }

#pragma unroll
        for (int r = 0; r < 4; r++) {
            float l = l_i[r];
            l += __shfl_xor(l, 1);
            l += __shfl_xor(l, 2);
            l += __shfl_xor(l, 4);
            l += __shfl_xor(l, 8);
            float inv = 1.f / l;
            size_t row = rowbase + qq * 128 + w * 16 + quad * 4 + r;
#pragma unroll
            for (int j = 0; j < 4; j++)
                zb[row * 1024 + hh * 64 + j * 16 + l16] = f2bf(o[j][r] * inv);
        }
    }
}

// ---------------------------------------------------------------------------
// LayerNorm(a + sum of 4 bf16 partial planes + bias) * g + beta.
// ---------------------------------------------------------------------------
template <int WRITE_BF16>
__global__ __launch_bounds__(256) void ln5_kernel(const float* __restrict__ a,
                                                  const unsigned short* __restrict__ q0,
                                                  const unsigned short* __restrict__ q1,
                                                  const unsigned short* __restrict__ q2,
                                                  const unsigned short* __restrict__ q3,
                                                  const float* __restrict__ bias,
                                                  const float* __restrict__ g,
                                                  const float* __restrict__ be,
                                                  float* __restrict__ out,
                                                  unsigned short* __restrict__ out_bf) {
    __shared__ float s1[256], s2[256];
    const int row = blockIdx.x;
    const int t   = threadIdx.x;
    const size_t base = (size_t)row * E_ + t * 4;

    float4 ya = *(const float4*)&a[base];
    ushort4 u0 = *(const ushort4*)&q0[base];
    ushort4 u1 = *(const ushort4*)&q1[base];
    ushort4 u2 = *(const ushort4*)&q2[base];
    ushort4 u3 = *(const ushort4*)&q3[base];
    float4 bb = *(const float4*)&bias[t * 4];
    float y0 = ya.x + bb.x + bf2f(u0.x) + bf2f(u1.x) + bf2f(u2.x) + bf2f(u3.x);
    float y1 = ya.y + bb.y + bf2f(u0.y) + bf2f(u1.y) + bf2f(u2.y) + bf2f(u3.y);
    float y2 = ya.z + bb.z + bf2f(u0.z) + bf2f(u1.z) + bf2f(u2.z) + bf2f(u3.z);
    float y3 = ya.w + bb.w + bf2f(u0.w) + bf2f(u1.w) + bf2f(u2.w) + bf2f(u3.w);

    s1[t] = y0 + y1 + y2 + y3;
    s2[t] = y0 * y0 + y1 * y1 + y2 * y2 + y3 * y3;
    __syncthreads();
    for (int off = 128; off > 0; off >>= 1) {
        if (t < off) { s1[t] += s1[t + off]; s2[t] += s2[t + off]; }
        __syncthreads();
    }
    float mean = s1[0] * (1.0f / E_);
    float var  = s2[0] * (1.0f / E_) - mean * mean;
    float rstd = rsqrtf(var + 1e-5f);

    float4 gv = *(const float4*)&g[t * 4];
    float4 bv = *(const float4*)&be[t * 4];
    float4 ov;
    ov.x = (y0 - mean) * rstd * gv.x + bv.x;
    ov.y = (y1 - mean) * rstd * gv.y + bv.y;
    ov.z = (y2 - mean) * rstd * gv.z + bv.z;
    ov.w = (y3 - mean) * rstd * gv.w + bv.w;
    *(float4*)&out[base] = ov;
    if (WRITE_BF16) {
        ushort4 pk = { f2bf(ov.x), f2bf(ov.y), f2bf(ov.z), f2bf(ov.w) };
        *(ushort4*)&out_bf[base] = pk;
    }
}

// ---------------------------------------------------------------------------
extern "C" void kernel_launch(void* const* d_in, const int* in_sizes, int n_in,
                              void* d_out, int out_size, void* d_ws, size_t ws_size,
                              hipStream_t stream)
{
    const float* x     = (const float*)d_in[0];
    const float* Wq    = (const float*)d_in[2];
    const float* bq    = (const float*)d_in[3];
    const float* Wk    = (const float*)d_in[4];
    const float* bk    = (const float*)d_in[5];
    const float* Wv    = (const float*)d_in[6];
    const float* bv    = (const float*)d_in[7];
    const float* Wo    = (const float*)d_in[8];
    const float* bo    = (const float*)d_in[9];
    const float* W1    = (const float*)d_in[10];
    const float* c1    = (const float*)d_in[11];
    const float* W2    = (const float*)d_in[12];
    const float* c2    = (const float*)d_in[13];
    const float* g1    = (const float*)d_in[14];
    const float* beta1 = (const float*)d_in[15];
    const float* g2    = (const float*)d_in[16];
    const float* beta2 = (const float*)d_in[17];
    float* out = (float*)d_out;

    const size_t MB = 1024 * 1024;
    char* w = (char*)d_ws;
    unsigned short* xb    = (unsigned short*)(w + 0 * MB);    // [0,8)   prep..QKV
    unsigned short* Wqkvt = (unsigned short*)(w + 8 * MB);    // [8,14)
    unsigned short* Wot   = (unsigned short*)(w + 14 * MB);   // [14,16)
    unsigned short* W1t   = (unsigned short*)(w + 16 * MB);   // [16,24)
    unsigned short* W2t   = (unsigned short*)(w + 24 * MB);   // [24,32)
    float*          bqkv  = (float*)(w + 32 * MB);            // [32,33)
    unsigned short* qkv   = (unsigned short*)(w + 33 * MB);   // [33,57)  QKV..attn
    unsigned short* zb    = (unsigned short*)(w + 57 * MB);   // [57,65)  attn..Wo
    float*          h     = (float*)(w + 65 * MB);            // [65,81)  LN1..LN2
    unsigned short* vtg   = (unsigned short*)(w + 89 * MB);   // [89,97)  vT..attn
    // Wo partials (bf16, 8 MB each): over dead qkv + dead vtg
    unsigned short* ap0   = (unsigned short*)(w + 33 * MB);
    unsigned short* ap1   = (unsigned short*)(w + 41 * MB);
    unsigned short* ap2   = (unsigned short*)(w + 49 * MB);
    unsigned short* ap3   = (unsigned short*)(w + 89 * MB);
    unsigned short* hb    = (unsigned short*)(w + 0 * MB);    // LN1..FFN1 (over xb)
    unsigned short* ff1b  = (unsigned short*)(w + 33 * MB);   // FFN1..FFN2 [33,65)
    // FFN2 partials (bf16): over dead hb/Wqkvt/Wot/W1t + tail
    unsigned short* fp0   = (unsigned short*)(w + 0 * MB);
    unsigned short* fp1   = (unsigned short*)(w + 8 * MB);
    unsigned short* fp2   = (unsigned short*)(w + 16 * MB);
    unsigned short* fp3   = (unsigned short*)(w + 81 * MB);

    static bool lds_inited = false;
    if (!lds_inited) {
        (void)hipFuncSetAttribute((const void*)&gemm256<0, 0>,
                                  hipFuncAttributeMaxDynamicSharedMemorySize, 131072);
        (void)hipFuncSetAttribute((const void*)&gemm256<1, 0>,
                                  hipFuncAttributeMaxDynamicSharedMemorySize, 131072);
        (void)hipFuncSetAttribute((const void*)&gemm256<0, 1>,
                                  hipFuncAttributeMaxDynamicSharedMemorySize, 131072);
        lds_inited = true;
    }

    dim3 blk(256);
    dim3 blk2(512);

    prep<<<dim3(16396), blk, 0, stream>>>(x, Wq, Wk, Wv, bq, bk, bv, Wo, W1, W2,
                                          xb, Wqkvt, Wot, W1t, W2t, bqkv);

    // QKV: M=4096, N=3072 -> 16x12 tiles = 192 blocks
    gemm256<0, 0><<<dim3(192), blk2, 131072, stream>>>(xb, Wqkvt, bqkv,
                                                       qkv, nullptr, nullptr, nullptr,
                                                       M_, 3072, E_);

    v_transpose_perm<<<dim3(L_ / 64, H_, B_), blk, 0, stream>>>(qkv, vtg);

    // attn v7: uniform-work pairs, grid 256 (1 block/CU)
    attn_mfma<<<dim3(256), blk2, 0, stream>>>(qkv, vtg, zb);

    // Wo: N=1024 -> 4 n-tiles, split-K=4 -> 256 blocks (KT=4 per plane)
    gemm256<0, 1><<<dim3(256), blk2, 131072, stream>>>(zb, Wot, nullptr,
                                                       ap0, ap1, ap2, ap3,
                                                       M_, E_, E_);

    ln5_kernel<1><<<dim3(M_), blk, 0, stream>>>(x, ap0, ap1, ap2, ap3, bo, g1, beta1, h, hb);

    // FFN1: M=4096, N=4096 -> 16x16 = 256 blocks
    gemm256<1, 0><<<dim3(256), blk2, 131072, stream>>>(hb, W1t, c1,
                                                       ff1b, nullptr, nullptr, nullptr,
                                                       M_, DFF, E_);

    // FFN2: N=1024 -> 4 n-tiles, split-K=4 -> 256 blocks (KT=16 per plane)
    gemm256<0, 1><<<dim3(256), blk2, 131072, stream>>>(ff1b, W2t, nullptr,
                                                       fp0, fp1, fp2, fp3,
                                                       M_, E_, DFF);

    ln5_kernel<0><<<dim3(M_), blk, 0, stream>>>(h, fp0, fp1, fp2, fp3, c2, g2, beta2, out, nullptr);
}

// Round 6
// 335.638 us; speedup vs baseline: 1.1238x; 1.0059x over previous
//
#include <hip/hip_runtime.h>
#include <hip/hip_bf16.h>
#include <math.h>

#define B_   2
#define L_   2048
#define E_   1024
#define H_   16
#define DH   64
#define DFF  4096
#define M_   4096
#define APAD 72
#define SCALE_Q 0.18033688011112042f   // log2(e)/8, folded into Wq/bq

typedef __attribute__((ext_vector_type(8))) short short8;
typedef __attribute__((ext_vector_type(4))) float f32x4;
typedef __bf16 bf16x8 __attribute__((ext_vector_type(8)));

__device__ __forceinline__ float bf2f(unsigned short u) {
    return __uint_as_float(((unsigned)u) << 16);
}
__device__ __forceinline__ unsigned short f2bf(float f) {
    unsigned u = __float_as_uint(f);
    return (unsigned short)((u + 0x7fff + ((u >> 16) & 1)) >> 16);
}
__device__ __forceinline__ unsigned pk_trunc(float lo, float hi) {
    return (__float_as_uint(lo) >> 16) | (__float_as_uint(hi) & 0xffff0000u);
}

// Async global->LDS, 16B/lane. LDS dest = wave-uniform base + lane*16B.
__device__ __forceinline__ void gld16(const unsigned short* g, unsigned short* l) {
    __builtin_amdgcn_global_load_lds(
        (const __attribute__((address_space(1))) void*)g,
        (__attribute__((address_space(3))) void*)l, 16, 0, 0);
}

// ---------------------------------------------------------------------------
// Fused preprocessing (unchanged).
// ---------------------------------------------------------------------------
__global__ __launch_bounds__(256) void prep(const float* __restrict__ x,
                                            const float* __restrict__ Wq,
                                            const float* __restrict__ Wk,
                                            const float* __restrict__ Wv,
                                            const float* __restrict__ bq,
                                            const float* __restrict__ bk,
                                            const float* __restrict__ bv,
                                            const float* __restrict__ Wo,
                                            const float* __restrict__ W1,
                                            const float* __restrict__ W2,
                                            unsigned short* __restrict__ xb,
                                            unsigned short* __restrict__ Wqkvt,
                                            unsigned short* __restrict__ Wot,
                                            unsigned short* __restrict__ W1t,
                                            unsigned short* __restrict__ W2t,
                                            float* __restrict__ bqkv) {
    __shared__ float tile[32][33];
    int bid = blockIdx.x;
    const int t = threadIdx.x;

    if (bid < 4096) {                      // x -> bf16
        int i = (bid * 256 + t) * 4;
        float4 v = *(const float4*)&x[i];
        ushort4 pk = { f2bf(v.x), f2bf(v.y), f2bf(v.z), f2bf(v.w) };
        *(ushort4*)&xb[i] = pk;
        return;
    }
    bid -= 4096;

    const float* in; unsigned short* outp; int R, C, r0, c0; float sc = 1.f;
    if (bid < 3072) {                      // Wqkv: per-head [E][DH] -> [DH][E]
        int xq = bid & 1, yq = (bid >> 1) & 31, wh = bid >> 6;
        int which = wh >> 4, h = wh & 15;
        in   = (which == 0 ? Wq : which == 1 ? Wk : Wv) + (size_t)h * E_ * DH;
        outp = Wqkvt + ((size_t)which * 1024 + h * 64) * 1024;
        R = E_; C = DH; r0 = yq * 32; c0 = xq * 32;
        if (which == 0) sc = SCALE_Q;
    } else if (bid < 4096) {               // Wo [E][E]
        bid -= 3072;
        in = Wo; outp = Wot; R = E_; C = E_;
        c0 = (bid & 31) * 32; r0 = (bid >> 5) * 32;
    } else if (bid < 8192) {               // W1 [E][DFF]
        bid -= 4096;
        in = W1; outp = W1t; R = E_; C = DFF;
        c0 = (bid & 127) * 32; r0 = (bid >> 7) * 32;
    } else if (bid < 12288) {              // W2 [DFF][E]
        bid -= 8192;
        in = W2; outp = W2t; R = DFF; C = E_;
        c0 = (bid & 31) * 32; r0 = (bid >> 5) * 32;
    } else {                               // bqkv
        bid -= 12288;
        int n = bid * 256 + t;
        bqkv[n] = n < 1024 ? bq[n] * SCALE_Q : n < 2048 ? bk[n - 1024] : bv[n - 2048];
        return;
    }

    const int tx = t & 31, tq = t >> 5;
#pragma unroll
    for (int s2 = 0; s2 < 4; s2++)
        tile[tq * 4 + s2][tx] = in[(size_t)(r0 + tq * 4 + s2) * C + c0 + tx] * sc;
    __syncthreads();
#pragma unroll
    for (int s2 = 0; s2 < 4; s2++)
        outp[(size_t)(c0 + tq * 4 + s2) * R + r0 + tx] = f2bf(tile[tx][tq * 4 + s2]);
}

// ---------------------------------------------------------------------------
// V pre-transpose with pi-permuted columns (unchanged).
// ---------------------------------------------------------------------------
__global__ __launch_bounds__(256) void v_transpose_perm(const unsigned short* __restrict__ qkv,
                                                        unsigned short* __restrict__ vtg) {
    __shared__ unsigned short tile[64 * APAD];
    const int t  = threadIdx.x;
    const int kt = blockIdx.x, hh = blockIdx.y, b = blockIdx.z;
    const int rr0 = t >> 3, o8 = (t & 7) * 8, rr1 = rr0 + 32;
    const size_t gbase = ((size_t)b * L_ + kt * 64) * 3072 + 2048 + hh * 64;
    *(short8*)&tile[rr0 * APAD + o8] = *(const short8*)&qkv[gbase + (size_t)rr0 * 3072 + o8];
    *(short8*)&tile[rr1 * APAD + o8] = *(const short8*)&qkv[gbase + (size_t)rr1 * 3072 + o8];
    __syncthreads();
    const size_t obase = ((size_t)(b * H_ + hh) * 64) * (size_t)L_ + kt * 64;
    const int a = t & 15, d0 = (t >> 4) * 4;
#pragma unroll
    for (int s2 = 0; s2 < 4; s2++) {
        int d = d0 + s2;
        ushort4 pk = { tile[(a +  0) * APAD + d], tile[(a + 16) * APAD + d],
                       tile[(a + 32) * APAD + d], tile[(a + 48) * APAD + d] };
        *(ushort4*)&vtg[obase + (size_t)d * L_ + 4 * a] = pk;
    }
}

// ---------------------------------------------------------------------------
// 256x256 8-phase bf16 GEMM (m201 template, plain HIP). Unchanged.
// ---------------------------------------------------------------------------
#define BAR() __builtin_amdgcn_s_barrier()
#define LGKM0() do { asm volatile("s_waitcnt lgkmcnt(0)" ::: "memory"); \
                     __builtin_amdgcn_sched_barrier(0); } while (0)

#define G256_READ_A(qr) do {                                                  \
    _Pragma("unroll") for (int mi = 0; mi < 4; mi++)                          \
    _Pragma("unroll") for (int ks = 0; ks < 2; ks++)                          \
        afr[mi][ks] = *(const bf16x8*)&As[bb + ((qr) * 128 + aRow + mi * 16) * 64 + (ks ? cs1 : cs0)]; \
} while (0)

#define G256_READ_B(qc) do {                                                  \
    _Pragma("unroll") for (int nj = 0; nj < 2; nj++)                          \
    _Pragma("unroll") for (int ks = 0; ks < 2; ks++)                          \
        bfr[qc][nj][ks] = *(const bf16x8*)&Bs[bb + ((qc) * 128 + bRow + nj * 16) * 64 + (ks ? cs1 : cs0)]; \
} while (0)

#define G256_MFMA(qr, qc) do {                                                \
    __builtin_amdgcn_s_setprio(1);                                            \
    _Pragma("unroll") for (int mi = 0; mi < 4; mi++)                          \
    _Pragma("unroll") for (int nj = 0; nj < 2; nj++)                          \
    _Pragma("unroll") for (int ks = 0; ks < 2; ks++)                          \
        acc[qr][qc][mi][nj] = __builtin_amdgcn_mfma_f32_16x16x32_bf16(        \
            afr[mi][ks], bfr[qc][nj][ks], acc[qr][qc][mi][nj], 0, 0, 0);      \
    __builtin_amdgcn_s_setprio(0);                                            \
} while (0)

template <int RELU, int SK>
__global__ __launch_bounds__(512, 2) void gemm256(const unsigned short* __restrict__ A,
                                                  const unsigned short* __restrict__ Bt,
                                                  const float* __restrict__ bias,
                                                  unsigned short* __restrict__ P0,
                                                  unsigned short* __restrict__ P1,
                                                  unsigned short* __restrict__ P2,
                                                  unsigned short* __restrict__ P3,
                                                  int M, int N, int K) {
    extern __shared__ __align__(16) unsigned short g_lds[];
    unsigned short* As = g_lds;            // [2][256][64] elems
    unsigned short* Bs = g_lds + 32768;    // [2][256][64] elems

    const int t    = threadIdx.x;
    const int lane = t & 63;
    const int w    = t >> 6;
    const int quad = lane >> 4;
    const int l16  = lane & 15;

    const int lin = blockIdx.x;
    const int xcd = lin & 7, s = lin >> 3;
    const int m0 = ((xcd << 1) | (s & 1)) * 256;
    const int rest = s >> 1;
    int n0, kbeg, KT;
    unsigned short* C;
    if (SK) {                       // N=1024 -> 4 n-tiles, split-K=4
        n0 = (rest & 3) * 256;
        const int z  = rest >> 2;
        const int K4 = K >> 2;
        kbeg = z * K4;
        KT   = K4 >> 6;
        C = (z == 0) ? P0 : (z == 1) ? P1 : (z == 2) ? P2 : P3;
    } else {
        n0 = rest * 256;
        kbeg = 0;
        KT   = K >> 6;
        C = P0;
    }

    // staging addressing: thread t covers (row = L*64 + (t>>3), slot t&7)
    const int srow = t >> 3;
    const int ksw  = ((t & 7) ^ (srow & 7)) * 8;
    const size_t aStage = (size_t)(m0 + srow) * K + kbeg + ksw;
    const size_t bStage = (size_t)(n0 + srow) * K + kbeg + ksw;

    auto stageA = [&](int buf, int h, int v) {
        size_t g = aStage + (size_t)(h * 128) * K + (size_t)v * 64;
        unsigned short* l = As + buf * 16384 + h * 8192 + w * 512;
        gld16(A + g, l);
        gld16(A + g + (size_t)64 * K, l + 4096);
    };
    auto stageB = [&](int buf, int h, int v) {
        size_t g = bStage + (size_t)(h * 128) * K + (size_t)v * 64;
        unsigned short* l = Bs + buf * 16384 + h * 8192 + w * 512;
        gld16(Bt + g, l);
        gld16(Bt + g + (size_t)64 * K, l + 4096);
    };

    const int aRow = (w >> 2) * 64 + l16;
    const int bRow = (w & 3) * 32 + l16;
    const int cs0  = (quad ^ (l16 & 7)) * 8;
    const int cs1  = cs0 ^ 32;

    f32x4 acc[2][2][4][2];
#pragma unroll
    for (int a1 = 0; a1 < 2; a1++)
#pragma unroll
        for (int a2 = 0; a2 < 2; a2++)
#pragma unroll
            for (int a3 = 0; a3 < 4; a3++)
#pragma unroll
                for (int a4 = 0; a4 < 2; a4++)
                    acc[a1][a2][a3][a4] = (f32x4){0.f, 0.f, 0.f, 0.f};

    bf16x8 afr[4][2], bfr[2][2][2];

    stageA(0, 0, 0); stageA(0, 1, 0); stageB(0, 0, 0); stageB(0, 1, 0);
    if (KT > 1) {
        stageA(1, 0, 1); stageB(1, 0, 1);
        asm volatile("s_waitcnt vmcnt(4)" ::: "memory");
    } else {
        asm volatile("s_waitcnt vmcnt(0)" ::: "memory");
    }
    BAR();

    for (int u = 0; u < KT; ++u) {
        const int bb = (u & 1) * 16384;
        const int nb = ((u + 1) & 1);

        // ---- P1 (0,0)
        G256_READ_A(0);
        G256_READ_B(0);
        if (u + 1 < KT) stageB(nb, 1, u + 1);        // B1(u+1)
        BAR(); LGKM0();
        G256_MFMA(0, 0);
        BAR();

        // ---- P2 (0,1)
        G256_READ_B(1);
        if (u + 1 < KT) stageA(nb, 1, u + 1);        // A1(u+1)
        BAR(); LGKM0();
        G256_MFMA(0, 1);
        BAR();

        // ---- P3 (1,0)
        G256_READ_A(1);
        if (u + 2 < KT) stageA(u & 1, 0, u + 2);     // A0(u+2)
        BAR(); LGKM0();
        G256_MFMA(1, 0);
        BAR();

        // ---- P4 (1,1)
        if (u + 2 < KT) {
            stageB(u & 1, 0, u + 2);                 // B0(u+2)
            asm volatile("s_waitcnt vmcnt(4)" ::: "memory");
        } else {
            asm volatile("s_waitcnt vmcnt(0)" ::: "memory");
        }
        BAR(); LGKM0();
        G256_MFMA(1, 1);
        BAR();
    }

#pragma unroll
    for (int qr = 0; qr < 2; qr++)
#pragma unroll
        for (int qc = 0; qc < 2; qc++)
#pragma unroll
            for (int nj = 0; nj < 2; nj++) {
                const int col = n0 + qc * 128 + (w & 3) * 32 + nj * 16 + l16;
                const float bv = SK ? 0.f : bias[col];
#pragma unroll
                for (int mi = 0; mi < 4; mi++) {
                    const int row = m0 + qr * 128 + (w >> 2) * 64 + mi * 16 + quad * 4;
#pragma unroll
                    for (int r = 0; r < 4; r++) {
                        float v = acc[qr][qc][mi][nj][r] + bv;
                        if (RELU) v = fmaxf(v, 0.f);
                        C[(size_t)(row + r) * N + col] = f2bf(v);
                    }
                }
            }
}

// ---------------------------------------------------------------------------
// MFMA flash attention v8: 4 waves x 32 q-rows (g=2, 256 threads) — the
// LDS-traffic-efficient shape (20 b128/wave/tile for 128 q-rows, half of
// v7's per-row traffic). Uniform work via complementary-pair + even/odd
// K-tile split-K: each block does (qq+1)+(15-qq+1) = 17 tiles exactly.
// Grid = 512 = 2 independent blocks/CU (mutual latency hiding, no lockstep).
// Writes unnormalized fp32 O-partials + l-partials; attn_combine normalizes.
// ---------------------------------------------------------------------------
__global__ __launch_bounds__(256, 2) void attn_mfma(const unsigned short* __restrict__ qkv,
                                                    const unsigned short* __restrict__ vtg,
                                                    float* __restrict__ oA,
                                                    float* __restrict__ oB,
                                                    float* __restrict__ lA,
                                                    float* __restrict__ lB) {
    __shared__ __align__(16) unsigned short ks[2][64 * APAD];
    __shared__ __align__(16) unsigned short vt[64 * APAD];
    __shared__ __align__(16) unsigned short ps[128 * APAD];

    const int t    = threadIdx.x;
    const int lane = t & 63;
    const int w    = t >> 6;          // 0..3, each wave owns 32 q-rows
    const int l16  = lane & 15;
    const int quad = lane >> 4;

    const int lin  = blockIdx.x;      // 0..511
    const int unit = lin >> 8;        // 0 = even K-tiles, 1 = odd
    const int l8   = lin & 255;
    const int xcd  = l8 & 7;
    const int s    = l8 >> 3;
    const int hh   = xcd * 2 + (s & 1);
    const int rest = s >> 1;          // 0..15
    const int b    = rest & 1;
    const int pair = rest >> 1;       // 0..7

    float* __restrict__ oP = unit ? oB : oA;
    float* __restrict__ lP = unit ? lB : lA;

    const size_t rowbase = (size_t)b * L_;
    const size_t vbase   = ((size_t)(b * H_ + hh) * 64) * (size_t)L_;
    const int rr0 = t >> 3, o8 = (t & 7) * 8, rr1 = rr0 + 32;

    for (int ph = 0; ph < 2; ph++) {
        const int qq = ph ? pair : 15 - pair;
        const int cnt = qq + 1;            // tiles for this unit this phase

        // Q fragments: wave w covers rows qq*128 + w*32 + g*16 .. +15
        bf16x8 qf[2][2];
#pragma unroll
        for (int g = 0; g < 2; g++) {
            size_t qrow = rowbase + qq * 128 + w * 32 + g * 16 + l16;
#pragma unroll
            for (int c = 0; c < 2; c++)
                qf[g][c] = *(const bf16x8*)&qkv[qrow * 3072 + hh * 64 + c * 32 + quad * 8];
        }

        f32x4 o[2][4];
#pragma unroll
        for (int g = 0; g < 2; g++)
#pragma unroll
            for (int j = 0; j < 4; j++) o[g][j] = (f32x4){0.f, 0.f, 0.f, 0.f};
        float l_i[2][4] = {};

        {   // preload first tile (kt = unit)
            size_t kg = (rowbase + unit * 64) * 3072 + 1024 + hh * 64;
            short8 k0 = *(const short8*)&qkv[kg + (size_t)rr0 * 3072 + o8];
            short8 k1 = *(const short8*)&qkv[kg + (size_t)rr1 * 3072 + o8];
            short8 v0 = *(const short8*)&vtg[vbase + unit * 64 + (size_t)rr0 * L_ + o8];
            short8 v1 = *(const short8*)&vtg[vbase + unit * 64 + (size_t)rr1 * L_ + o8];
            *(short8*)&ks[0][rr0 * APAD + o8] = k0;
            *(short8*)&ks[0][rr1 * APAD + o8] = k1;
            *(short8*)&vt[rr0 * APAD + o8] = v0;
            *(short8*)&vt[rr1 * APAD + o8] = v1;
        }

        short8 kr0, kr1, vr0, vr1;
        for (int i = 0; i < cnt; i++) {
            const int kt = unit + 2 * i;
            const int p  = i & 1;
            __syncthreads();

            if (i + 1 < cnt) {                 // prefetch tile kt+2
                size_t kg = (rowbase + (kt + 2) * 64) * 3072 + 1024 + hh * 64;
                kr0 = *(const short8*)&qkv[kg + (size_t)rr0 * 3072 + o8];
                kr1 = *(const short8*)&qkv[kg + (size_t)rr1 * 3072 + o8];
                size_t vg = vbase + (kt + 2) * 64;
                vr0 = *(const short8*)&vtg[vg + (size_t)rr0 * L_ + o8];
                vr1 = *(const short8*)&vtg[vg + (size_t)rr1 * L_ + o8];
            }

            f32x4 s4[2][4];
#pragma unroll
            for (int g = 0; g < 2; g++)
#pragma unroll
                for (int j = 0; j < 4; j++) s4[g][j] = (f32x4){0.f, 0.f, 0.f, 0.f};
            __builtin_amdgcn_s_setprio(1);
#pragma unroll
            for (int c = 0; c < 2; c++)
#pragma unroll
                for (int j = 0; j < 4; j++) {
                    bf16x8 kf = *(const bf16x8*)&ks[p][(j * 16 + l16) * APAD + c * 32 + quad * 8];
#pragma unroll
                    for (int g = 0; g < 2; g++)
                        s4[g][j] = __builtin_amdgcn_mfma_f32_16x16x32_bf16(qf[g][c], kf, s4[g][j], 0, 0, 0);
                }
            __builtin_amdgcn_s_setprio(0);

            if (kt >= 2 * qq) {                // diagonal tile: causal mask
#pragma unroll
                for (int g = 0; g < 2; g++)
#pragma unroll
                    for (int j = 0; j < 4; j++) {
                        int lk = kt * 64 + j * 16 + l16;
#pragma unroll
                        for (int r = 0; r < 4; r++)
                            if (lk > qq * 128 + w * 32 + g * 16 + quad * 4 + r)
                                s4[g][j][r] = -INFINITY;
                    }
            }

#pragma unroll
            for (int g = 0; g < 2; g++)
#pragma unroll
                for (int r = 0; r < 4; r++) {
                    float p0 = __builtin_amdgcn_exp2f(s4[g][0][r]);
                    float p1 = __builtin_amdgcn_exp2f(s4[g][1][r]);
                    float p2 = __builtin_amdgcn_exp2f(s4[g][2][r]);
                    float p3 = __builtin_amdgcn_exp2f(s4[g][3][r]);
                    l_i[g][r] += (p0 + p1) + (p2 + p3);
                    uint2 pk = { pk_trunc(p0, p1), pk_trunc(p2, p3) };
                    *(uint2*)&ps[(w * 32 + g * 16 + quad * 4 + r) * APAD + 4 * l16] = pk;
                }

            __builtin_amdgcn_s_waitcnt(0xc07f);   // lgkmcnt(0): own-row P visible

            __builtin_amdgcn_s_setprio(1);
#pragma unroll
            for (int c = 0; c < 2; c++) {
                bf16x8 pf[2];
#pragma unroll
                for (int g = 0; g < 2; g++)
                    pf[g] = *(const bf16x8*)&ps[(w * 32 + g * 16 + l16) * APAD + c * 32 + quad * 8];
#pragma unroll
                for (int j = 0; j < 4; j++) {
                    bf16x8 vf = *(const bf16x8*)&vt[(j * 16 + l16) * APAD + c * 32 + quad * 8];
#pragma unroll
                    for (int g = 0; g < 2; g++)
                        o[g][j] = __builtin_amdgcn_mfma_f32_16x16x32_bf16(pf[g], vf, o[g][j], 0, 0, 0);
                }
            }
            __builtin_amdgcn_s_setprio(0);

            __syncthreads();
            if (i + 1 < cnt) {
                *(short8*)&ks[p ^ 1][rr0 * APAD + o8] = kr0;
                *(short8*)&ks[p ^ 1][rr1 * APAD + o8] = kr1;
                *(short8*)&vt[rr0 * APAD + o8] = vr0;
                *(short8*)&vt[rr1 * APAD + o8] = vr1;
            }
        }

        // phase epilogue: store unnormalized partials
#pragma unroll
        for (int g = 0; g < 2; g++)
#pragma unroll
            for (int r = 0; r < 4; r++) {
                float l = l_i[g][r];
                l += __shfl_xor(l, 1);
                l += __shfl_xor(l, 2);
                l += __shfl_xor(l, 4);
                l += __shfl_xor(l, 8);
                int rowq = qq * 128 + w * 32 + g * 16 + quad * 4 + r;
                size_t grow = (size_t)(b * H_ + hh) * L_ + rowq;
                if (l16 == 0) lP[grow] = l;
#pragma unroll
                for (int j = 0; j < 4; j++)
                    oP[grow * 64 + j * 16 + l16] = o[g][j][r];
            }
    }
}

// ---------------------------------------------------------------------------
// Combine the two attention split-K partials: zb = (oA+oB)/(lA+lB), bf16.
// ---------------------------------------------------------------------------
__global__ __launch_bounds__(256) void attn_combine(const float* __restrict__ oA,
                                                    const float* __restrict__ oB,
                                                    const float* __restrict__ lA,
                                                    const float* __restrict__ lB,
                                                    unsigned short* __restrict__ zb) {
    const int t = threadIdx.x;
    const size_t idx4 = ((size_t)blockIdx.x * 256 + t) * 4;
    const size_t row  = idx4 >> 6;          // 0 .. B*H*L-1
    const int    col  = (int)(idx4 & 63);

    float inv = 1.f / (lA[row] + lB[row]);
    float4 a = *(const float4*)&oA[idx4];
    float4 c = *(const float4*)&oB[idx4];

    const int bq   = (int)(row >> 15);          // batch
    const int hh   = (int)((row >> 11) & 15);   // head
    const int rowq = (int)(row & 2047);
    size_t z = ((size_t)(bq * L_ + rowq)) * 1024 + hh * 64 + col;
    ushort4 pk = { f2bf((a.x + c.x) * inv), f2bf((a.y + c.y) * inv),
                   f2bf((a.z + c.z) * inv), f2bf((a.w + c.w) * inv) };
    *(ushort4*)&zb[z] = pk;
}

// ---------------------------------------------------------------------------
// LayerNorm(a + sum of 4 bf16 partial planes + bias) * g + beta.
// ---------------------------------------------------------------------------
template <int WRITE_BF16>
__global__ __launch_bounds__(256) void ln5_kernel(const float* __restrict__ a,
                                                  const unsigned short* __restrict__ q0,
                                                  const unsigned short* __restrict__ q1,
                                                  const unsigned short* __restrict__ q2,
                                                  const unsigned short* __restrict__ q3,
                                                  const float* __restrict__ bias,
                                                  const float* __restrict__ g,
                                                  const float* __restrict__ be,
                                                  float* __restrict__ out,
                                                  unsigned short* __restrict__ out_bf) {
    __shared__ float s1[256], s2[256];
    const int row = blockIdx.x;
    const int t   = threadIdx.x;
    const size_t base = (size_t)row * E_ + t * 4;

    float4 ya = *(const float4*)&a[base];
    ushort4 u0 = *(const ushort4*)&q0[base];
    ushort4 u1 = *(const ushort4*)&q1[base];
    ushort4 u2 = *(const ushort4*)&q2[base];
    ushort4 u3 = *(const ushort4*)&q3[base];
    float4 bb = *(const float4*)&bias[t * 4];
    float y0 = ya.x + bb.x + bf2f(u0.x) + bf2f(u1.x) + bf2f(u2.x) + bf2f(u3.x);
    float y1 = ya.y + bb.y + bf2f(u0.y) + bf2f(u1.y) + bf2f(u2.y) + bf2f(u3.y);
    float y2 = ya.z + bb.z + bf2f(u0.z) + bf2f(u1.z) + bf2f(u2.z) + bf2f(u3.z);
    float y3 = ya.w + bb.w + bf2f(u0.w) + bf2f(u1.w) + bf2f(u2.w) + bf2f(u3.w);

    s1[t] = y0 + y1 + y2 + y3;
    s2[t] = y0 * y0 + y1 * y1 + y2 * y2 + y3 * y3;
    __syncthreads();
    for (int off = 128; off > 0; off >>= 1) {
        if (t < off) { s1[t] += s1[t + off]; s2[t] += s2[t + off]; }
        __syncthreads();
    }
    float mean = s1[0] * (1.0f / E_);
    float var  = s2[0] * (1.0f / E_) - mean * mean;
    float rstd = rsqrtf(var + 1e-5f);

    float4 gv = *(const float4*)&g[t * 4];
    float4 bv = *(const float4*)&be[t * 4];
    float4 ov;
    ov.x = (y0 - mean) * rstd * gv.x + bv.x;
    ov.y = (y1 - mean) * rstd * gv.y + bv.y;
    ov.z = (y2 - mean) * rstd * gv.z + bv.z;
    ov.w = (y3 - mean) * rstd * gv.w + bv.w;
    *(float4*)&out[base] = ov;
    if (WRITE_BF16) {
        ushort4 pk = { f2bf(ov.x), f2bf(ov.y), f2bf(ov.z), f2bf(ov.w) };
        *(ushort4*)&out_bf[base] = pk;
    }
}

// ---------------------------------------------------------------------------
extern "C" void kernel_launch(void* const* d_in, const int* in_sizes, int n_in,
                              void* d_out, int out_size, void* d_ws, size_t ws_size,
                              hipStream_t stream)
{
    const float* x     = (const float*)d_in[0];
    const float* Wq    = (const float*)d_in[2];
    const float* bq    = (const float*)d_in[3];
    const float* Wk    = (const float*)d_in[4];
    const float* bk    = (const float*)d_in[5];
    const float* Wv    = (const float*)d_in[6];
    const float* bv    = (const float*)d_in[7];
    const float* Wo    = (const float*)d_in[8];
    const float* bo    = (const float*)d_in[9];
    const float* W1    = (const float*)d_in[10];
    const float* c1    = (const float*)d_in[11];
    const float* W2    = (const float*)d_in[12];
    const float* c2    = (const float*)d_in[13];
    const float* g1    = (const float*)d_in[14];
    const float* beta1 = (const float*)d_in[15];
    const float* g2    = (const float*)d_in[16];
    const float* beta2 = (const float*)d_in[17];
    float* out = (float*)d_out;

    const size_t MB = 1024 * 1024;
    char* w = (char*)d_ws;
    unsigned short* xb    = (unsigned short*)(w + 0 * MB);    // [0,8)   prep..QKV
    unsigned short* Wqkvt = (unsigned short*)(w + 8 * MB);    // [8,14)
    unsigned short* Wot   = (unsigned short*)(w + 14 * MB);   // [14,16)
    unsigned short* W1t   = (unsigned short*)(w + 16 * MB);   // [16,24)
    unsigned short* W2t   = (unsigned short*)(w + 24 * MB);   // [24,32)
    float*          bqkv  = (float*)(w + 32 * MB);            // [32,33)  prep..QKV
    unsigned short* qkv   = (unsigned short*)(w + 33 * MB);   // [33,57)  QKV..attn
    float*          h     = (float*)(w + 65 * MB);            // [65,81)  LN1..LN2
    unsigned short* vtg   = (unsigned short*)(w + 89 * MB);   // [89,97)  vT..attn
    // attention split-K partials (attn..combine window):
    float*          oPA   = (float*)(w + 57 * MB);            // [57,73)  fp32
    float*          oPB   = (float*)(w + 73 * MB);            // [73,89)  fp32
    float*          lPA   = (float*)(w + 32 * MB);            // over dead bqkv
    float*          lPB   = (float*)(w + 32 * MB + 262144);
    unsigned short* zb    = (unsigned short*)(w + 0 * MB);    // combine..Wo (over dead xb)
    // Wo partials (bf16, 8 MB each): over dead qkv + dead vtg
    unsigned short* ap0   = (unsigned short*)(w + 33 * MB);
    unsigned short* ap1   = (unsigned short*)(w + 41 * MB);
    unsigned short* ap2   = (unsigned short*)(w + 49 * MB);
    unsigned short* ap3   = (unsigned short*)(w + 89 * MB);
    unsigned short* hb    = (unsigned short*)(w + 0 * MB);    // LN1..FFN1 (over zb, dead by then)
    unsigned short* ff1b  = (unsigned short*)(w + 33 * MB);   // FFN1..FFN2 [33,65)
    // FFN2 partials (bf16): over dead hb/Wqkvt/Wot/W1t + tail
    unsigned short* fp0   = (unsigned short*)(w + 0 * MB);
    unsigned short* fp1   = (unsigned short*)(w + 8 * MB);
    unsigned short* fp2   = (unsigned short*)(w + 16 * MB);
    unsigned short* fp3   = (unsigned short*)(w + 81 * MB);

    static bool lds_inited = false;
    if (!lds_inited) {
        (void)hipFuncSetAttribute((const void*)&gemm256<0, 0>,
                                  hipFuncAttributeMaxDynamicSharedMemorySize, 131072);
        (void)hipFuncSetAttribute((const void*)&gemm256<1, 0>,
                                  hipFuncAttributeMaxDynamicSharedMemorySize, 131072);
        (void)hipFuncSetAttribute((const void*)&gemm256<0, 1>,
                                  hipFuncAttributeMaxDynamicSharedMemorySize, 131072);
        lds_inited = true;
    }

    dim3 blk(256);
    dim3 blk2(512);

    prep<<<dim3(16396), blk, 0, stream>>>(x, Wq, Wk, Wv, bq, bk, bv, Wo, W1, W2,
                                          xb, Wqkvt, Wot, W1t, W2t, bqkv);

    // QKV: M=4096, N=3072 -> 16x12 tiles = 192 blocks
    gemm256<0, 0><<<dim3(192), blk2, 131072, stream>>>(xb, Wqkvt, bqkv,
                                                       qkv, nullptr, nullptr, nullptr,
                                                       M_, 3072, E_);

    v_transpose_perm<<<dim3(L_ / 64, H_, B_), blk, 0, stream>>>(qkv, vtg);

    // attn v8: split-K pairs, grid 512 (2 blocks/CU), 17 tiles each
    attn_mfma<<<dim3(512), blk, 0, stream>>>(qkv, vtg, oPA, oPB, lPA, lPB);

    // combine: B*H*L*64 fp32 elems, 4/thread -> 4096 blocks
    attn_combine<<<dim3(4096), blk, 0, stream>>>(oPA, oPB, lPA, lPB, zb);

    // Wo: N=1024 -> 4 n-tiles, split-K=4 -> 256 blocks (KT=4 per plane)
    gemm256<0, 1><<<dim3(256), blk2, 131072, stream>>>(zb, Wot, nullptr,
                                                       ap0, ap1, ap2, ap3,
                                                       M_, E_, E_);

    ln5_kernel<1><<<dim3(M_), blk, 0, stream>>>(x, ap0, ap1, ap2, ap3, bo, g1, beta1, h, hb);

    // FFN1: M=4096, N=4096 -> 16x16 = 256 blocks
    gemm256<1, 0><<<dim3(256), blk2, 131072, stream>>>(hb, W1t, c1,
                                                       ff1b, nullptr, nullptr, nullptr,
                                                       M_, DFF, E_);

    // FFN2: N=1024 -> 4 n-tiles, split-K=4 -> 256 blocks (KT=16 per plane)
    gemm256<0, 1><<<dim3(256), blk2, 131072, stream>>>(ff1b, W2t, nullptr,
                                                       fp0, fp1, fp2, fp3,
                                                       M_, E_, DFF);

    ln5_kernel<0><<<dim3(M_), blk, 0, stream>>>(h, fp0, fp1, fp2, fp3, c2, g2, beta2, out, nullptr);
}

// Round 7
// 330.033 us; speedup vs baseline: 1.1429x; 1.0170x over previous
//
#include <hip/hip_runtime.h>
#include <hip/hip_bf16.h>
#include <math.h>

#define B_   2
#define L_   2048
#define E_   1024
#define H_   16
#define DH   64
#define DFF  4096
#define M_   4096
#define APAD 72
#define SCALE_Q 0.18033688011112042f   // log2(e)/8, folded into Wq/bq

typedef __attribute__((ext_vector_type(8))) short short8;
typedef __attribute__((ext_vector_type(4))) float f32x4;
typedef __bf16 bf16x8 __attribute__((ext_vector_type(8)));

__device__ __forceinline__ float bf2f(unsigned short u) {
    return __uint_as_float(((unsigned)u) << 16);
}
__device__ __forceinline__ unsigned short f2bf(float f) {
    unsigned u = __float_as_uint(f);
    return (unsigned short)((u + 0x7fff + ((u >> 16) & 1)) >> 16);
}
__device__ __forceinline__ unsigned pk_trunc(float lo, float hi) {
    return (__float_as_uint(lo) >> 16) | (__float_as_uint(hi) & 0xffff0000u);
}

// Async global->LDS, 16B/lane. LDS dest = wave-uniform base + lane*16B.
__device__ __forceinline__ void gld16(const unsigned short* g, unsigned short* l) {
    __builtin_amdgcn_global_load_lds(
        (const __attribute__((address_space(1))) void*)g,
        (__attribute__((address_space(3))) void*)l, 16, 0, 0);
}

// ---------------------------------------------------------------------------
// Fused preprocessing (unchanged).
// ---------------------------------------------------------------------------
__global__ __launch_bounds__(256) void prep(const float* __restrict__ x,
                                            const float* __restrict__ Wq,
                                            const float* __restrict__ Wk,
                                            const float* __restrict__ Wv,
                                            const float* __restrict__ bq,
                                            const float* __restrict__ bk,
                                            const float* __restrict__ bv,
                                            const float* __restrict__ Wo,
                                            const float* __restrict__ W1,
                                            const float* __restrict__ W2,
                                            unsigned short* __restrict__ xb,
                                            unsigned short* __restrict__ Wqkvt,
                                            unsigned short* __restrict__ Wot,
                                            unsigned short* __restrict__ W1t,
                                            unsigned short* __restrict__ W2t,
                                            float* __restrict__ bqkv) {
    __shared__ float tile[32][33];
    int bid = blockIdx.x;
    const int t = threadIdx.x;

    if (bid < 4096) {                      // x -> bf16
        int i = (bid * 256 + t) * 4;
        float4 v = *(const float4*)&x[i];
        ushort4 pk = { f2bf(v.x), f2bf(v.y), f2bf(v.z), f2bf(v.w) };
        *(ushort4*)&xb[i] = pk;
        return;
    }
    bid -= 4096;

    const float* in; unsigned short* outp; int R, C, r0, c0; float sc = 1.f;
    if (bid < 3072) {                      // Wqkv: per-head [E][DH] -> [DH][E]
        int xq = bid & 1, yq = (bid >> 1) & 31, wh = bid >> 6;
        int which = wh >> 4, h = wh & 15;
        in   = (which == 0 ? Wq : which == 1 ? Wk : Wv) + (size_t)h * E_ * DH;
        outp = Wqkvt + ((size_t)which * 1024 + h * 64) * 1024;
        R = E_; C = DH; r0 = yq * 32; c0 = xq * 32;
        if (which == 0) sc = SCALE_Q;
    } else if (bid < 4096) {               // Wo [E][E]
        bid -= 3072;
        in = Wo; outp = Wot; R = E_; C = E_;
        c0 = (bid & 31) * 32; r0 = (bid >> 5) * 32;
    } else if (bid < 8192) {               // W1 [E][DFF]
        bid -= 4096;
        in = W1; outp = W1t; R = E_; C = DFF;
        c0 = (bid & 127) * 32; r0 = (bid >> 7) * 32;
    } else if (bid < 12288) {              // W2 [DFF][E]
        bid -= 8192;
        in = W2; outp = W2t; R = DFF; C = E_;
        c0 = (bid & 31) * 32; r0 = (bid >> 5) * 32;
    } else {                               // bqkv
        bid -= 12288;
        int n = bid * 256 + t;
        bqkv[n] = n < 1024 ? bq[n] * SCALE_Q : n < 2048 ? bk[n - 1024] : bv[n - 2048];
        return;
    }

    const int tx = t & 31, tq = t >> 5;
#pragma unroll
    for (int s2 = 0; s2 < 4; s2++)
        tile[tq * 4 + s2][tx] = in[(size_t)(r0 + tq * 4 + s2) * C + c0 + tx] * sc;
    __syncthreads();
#pragma unroll
    for (int s2 = 0; s2 < 4; s2++)
        outp[(size_t)(c0 + tq * 4 + s2) * R + r0 + tx] = f2bf(tile[tx][tq * 4 + s2]);
}

// ---------------------------------------------------------------------------
// V pre-transpose with pi-permuted columns (unchanged).
// ---------------------------------------------------------------------------
__global__ __launch_bounds__(256) void v_transpose_perm(const unsigned short* __restrict__ qkv,
                                                        unsigned short* __restrict__ vtg) {
    __shared__ unsigned short tile[64 * APAD];
    const int t  = threadIdx.x;
    const int kt = blockIdx.x, hh = blockIdx.y, b = blockIdx.z;
    const int rr0 = t >> 3, o8 = (t & 7) * 8, rr1 = rr0 + 32;
    const size_t gbase = ((size_t)b * L_ + kt * 64) * 3072 + 2048 + hh * 64;
    *(short8*)&tile[rr0 * APAD + o8] = *(const short8*)&qkv[gbase + (size_t)rr0 * 3072 + o8];
    *(short8*)&tile[rr1 * APAD + o8] = *(const short8*)&qkv[gbase + (size_t)rr1 * 3072 + o8];
    __syncthreads();
    const size_t obase = ((size_t)(b * H_ + hh) * 64) * (size_t)L_ + kt * 64;
    const int a = t & 15, d0 = (t >> 4) * 4;
#pragma unroll
    for (int s2 = 0; s2 < 4; s2++) {
        int d = d0 + s2;
        ushort4 pk = { tile[(a +  0) * APAD + d], tile[(a + 16) * APAD + d],
                       tile[(a + 32) * APAD + d], tile[(a + 48) * APAD + d] };
        *(ushort4*)&vtg[obase + (size_t)d * L_ + 4 * a] = pk;
    }
}

// ---------------------------------------------------------------------------
// 256x256 8-phase bf16 GEMM (m201 template). R7 change: non-SK XCD chunk
// swizzle — each XCD owns a 4m x (Ntiles/2)n chunk so its L2 working set is
// A 2MB + B <=4MB (was 2m x ALL-n = 9MB, thrashing the 4MB L2 -> 3x fetch).
// ---------------------------------------------------------------------------
#define BAR() __builtin_amdgcn_s_barrier()
#define LGKM0() do { asm volatile("s_waitcnt lgkmcnt(0)" ::: "memory"); \
                     __builtin_amdgcn_sched_barrier(0); } while (0)

#define G256_READ_A(qr) do {                                                  \
    _Pragma("unroll") for (int mi = 0; mi < 4; mi++)                          \
    _Pragma("unroll") for (int ks = 0; ks < 2; ks++)                          \
        afr[mi][ks] = *(const bf16x8*)&As[bb + ((qr) * 128 + aRow + mi * 16) * 64 + (ks ? cs1 : cs0)]; \
} while (0)

#define G256_READ_B(qc) do {                                                  \
    _Pragma("unroll") for (int nj = 0; nj < 2; nj++)                          \
    _Pragma("unroll") for (int ks = 0; ks < 2; ks++)                          \
        bfr[qc][nj][ks] = *(const bf16x8*)&Bs[bb + ((qc) * 128 + bRow + nj * 16) * 64 + (ks ? cs1 : cs0)]; \
} while (0)

#define G256_MFMA(qr, qc) do {                                                \
    __builtin_amdgcn_s_setprio(1);                                            \
    _Pragma("unroll") for (int mi = 0; mi < 4; mi++)                          \
    _Pragma("unroll") for (int nj = 0; nj < 2; nj++)                          \
    _Pragma("unroll") for (int ks = 0; ks < 2; ks++)                          \
        acc[qr][qc][mi][nj] = __builtin_amdgcn_mfma_f32_16x16x32_bf16(        \
            afr[mi][ks], bfr[qc][nj][ks], acc[qr][qc][mi][nj], 0, 0, 0);      \
    __builtin_amdgcn_s_setprio(0);                                            \
} while (0)

template <int RELU, int SK>
__global__ __launch_bounds__(512, 2) void gemm256(const unsigned short* __restrict__ A,
                                                  const unsigned short* __restrict__ Bt,
                                                  const float* __restrict__ bias,
                                                  unsigned short* __restrict__ P0,
                                                  unsigned short* __restrict__ P1,
                                                  unsigned short* __restrict__ P2,
                                                  unsigned short* __restrict__ P3,
                                                  int M, int N, int K) {
    extern __shared__ __align__(16) unsigned short g_lds[];
    unsigned short* As = g_lds;            // [2][256][64] elems
    unsigned short* Bs = g_lds + 32768;    // [2][256][64] elems

    const int t    = threadIdx.x;
    const int lane = t & 63;
    const int w    = t >> 6;
    const int quad = lane >> 4;
    const int l16  = lane & 15;

    const int lin = blockIdx.x;
    const int xcd = lin & 7, s = lin >> 3;
    int m0, n0, kbeg, KT;
    unsigned short* C;
    if (SK) {                       // N=1024 -> 4 n-tiles, split-K=4
        m0 = ((xcd << 1) | (s & 1)) * 256;
        const int rest = s >> 1;
        n0 = (rest & 3) * 256;
        const int z  = rest >> 2;
        const int K4 = K >> 2;
        kbeg = z * K4;
        KT   = K4 >> 6;
        C = (z == 0) ? P0 : (z == 1) ? P1 : (z == 2) ? P2 : P3;
    } else {
        // chunk swizzle: XCD (x&3) owns m-quarter, (x>>2) owns n-half
        const int NT2 = (N >> 8) >> 1;     // n-tiles per XCD chunk
        m0 = (((xcd & 3) << 2) | (s & 3)) * 256;
        n0 = ((xcd >> 2) * NT2 + (s >> 2)) * 256;
        kbeg = 0;
        KT   = K >> 6;
        C = P0;
    }

    // staging addressing: thread t covers (row = L*64 + (t>>3), slot t&7)
    const int srow = t >> 3;
    const int ksw  = ((t & 7) ^ (srow & 7)) * 8;
    const size_t aStage = (size_t)(m0 + srow) * K + kbeg + ksw;
    const size_t bStage = (size_t)(n0 + srow) * K + kbeg + ksw;

    auto stageA = [&](int buf, int h, int v) {
        size_t g = aStage + (size_t)(h * 128) * K + (size_t)v * 64;
        unsigned short* l = As + buf * 16384 + h * 8192 + w * 512;
        gld16(A + g, l);
        gld16(A + g + (size_t)64 * K, l + 4096);
    };
    auto stageB = [&](int buf, int h, int v) {
        size_t g = bStage + (size_t)(h * 128) * K + (size_t)v * 64;
        unsigned short* l = Bs + buf * 16384 + h * 8192 + w * 512;
        gld16(Bt + g, l);
        gld16(Bt + g + (size_t)64 * K, l + 4096);
    };

    const int aRow = (w >> 2) * 64 + l16;
    const int bRow = (w & 3) * 32 + l16;
    const int cs0  = (quad ^ (l16 & 7)) * 8;
    const int cs1  = cs0 ^ 32;

    f32x4 acc[2][2][4][2];
#pragma unroll
    for (int a1 = 0; a1 < 2; a1++)
#pragma unroll
        for (int a2 = 0; a2 < 2; a2++)
#pragma unroll
            for (int a3 = 0; a3 < 4; a3++)
#pragma unroll
                for (int a4 = 0; a4 < 2; a4++)
                    acc[a1][a2][a3][a4] = (f32x4){0.f, 0.f, 0.f, 0.f};

    bf16x8 afr[4][2], bfr[2][2][2];

    stageA(0, 0, 0); stageA(0, 1, 0); stageB(0, 0, 0); stageB(0, 1, 0);
    if (KT > 1) {
        stageA(1, 0, 1); stageB(1, 0, 1);
        asm volatile("s_waitcnt vmcnt(4)" ::: "memory");
    } else {
        asm volatile("s_waitcnt vmcnt(0)" ::: "memory");
    }
    BAR();

    for (int u = 0; u < KT; ++u) {
        const int bb = (u & 1) * 16384;
        const int nb = ((u + 1) & 1);

        // ---- P1 (0,0)
        G256_READ_A(0);
        G256_READ_B(0);
        if (u + 1 < KT) stageB(nb, 1, u + 1);        // B1(u+1)
        BAR(); LGKM0();
        G256_MFMA(0, 0);
        BAR();

        // ---- P2 (0,1)
        G256_READ_B(1);
        if (u + 1 < KT) stageA(nb, 1, u + 1);        // A1(u+1)
        BAR(); LGKM0();
        G256_MFMA(0, 1);
        BAR();

        // ---- P3 (1,0)
        G256_READ_A(1);
        if (u + 2 < KT) stageA(u & 1, 0, u + 2);     // A0(u+2)
        BAR(); LGKM0();
        G256_MFMA(1, 0);
        BAR();

        // ---- P4 (1,1)
        if (u + 2 < KT) {
            stageB(u & 1, 0, u + 2);                 // B0(u+2)
            asm volatile("s_waitcnt vmcnt(4)" ::: "memory");
        } else {
            asm volatile("s_waitcnt vmcnt(0)" ::: "memory");
        }
        BAR(); LGKM0();
        G256_MFMA(1, 1);
        BAR();
    }

#pragma unroll
    for (int qr = 0; qr < 2; qr++)
#pragma unroll
        for (int qc = 0; qc < 2; qc++)
#pragma unroll
            for (int nj = 0; nj < 2; nj++) {
                const int col = n0 + qc * 128 + (w & 3) * 32 + nj * 16 + l16;
                const float bv = SK ? 0.f : bias[col];
#pragma unroll
                for (int mi = 0; mi < 4; mi++) {
                    const int row = m0 + qr * 128 + (w >> 2) * 64 + mi * 16 + quad * 4;
#pragma unroll
                    for (int r = 0; r < 4; r++) {
                        float v = acc[qr][qc][mi][nj][r] + bv;
                        if (RELU) v = fmaxf(v, 0.f);
                        C[(size_t)(row + r) * N + col] = f2bf(v);
                    }
                }
            }
}

// ---------------------------------------------------------------------------
// MFMA flash attention v8b: as v8 but O-partials stored bf16 (halves combine
// traffic; unnormalized magnitudes well within bf16 range, rel err 2^-8).
// ---------------------------------------------------------------------------
__global__ __launch_bounds__(256, 2) void attn_mfma(const unsigned short* __restrict__ qkv,
                                                    const unsigned short* __restrict__ vtg,
                                                    unsigned short* __restrict__ oA,
                                                    unsigned short* __restrict__ oB,
                                                    float* __restrict__ lA,
                                                    float* __restrict__ lB) {
    __shared__ __align__(16) unsigned short ks[2][64 * APAD];
    __shared__ __align__(16) unsigned short vt[64 * APAD];
    __shared__ __align__(16) unsigned short ps[128 * APAD];

    const int t    = threadIdx.x;
    const int lane = t & 63;
    const int w    = t >> 6;          // 0..3, each wave owns 32 q-rows
    const int l16  = lane & 15;
    const int quad = lane >> 4;

    const int lin  = blockIdx.x;      // 0..511
    const int unit = lin >> 8;        // 0 = even K-tiles, 1 = odd
    const int l8   = lin & 255;
    const int xcd  = l8 & 7;
    const int s    = l8 >> 3;
    const int hh   = xcd * 2 + (s & 1);
    const int rest = s >> 1;          // 0..15
    const int b    = rest & 1;
    const int pair = rest >> 1;       // 0..7

    unsigned short* __restrict__ oP = unit ? oB : oA;
    float* __restrict__ lP = unit ? lB : lA;

    const size_t rowbase = (size_t)b * L_;
    const size_t vbase   = ((size_t)(b * H_ + hh) * 64) * (size_t)L_;
    const int rr0 = t >> 3, o8 = (t & 7) * 8, rr1 = rr0 + 32;

    for (int ph = 0; ph < 2; ph++) {
        const int qq = ph ? pair : 15 - pair;
        const int cnt = qq + 1;            // tiles for this unit this phase

        // Q fragments: wave w covers rows qq*128 + w*32 + g*16 .. +15
        bf16x8 qf[2][2];
#pragma unroll
        for (int g = 0; g < 2; g++) {
            size_t qrow = rowbase + qq * 128 + w * 32 + g * 16 + l16;
#pragma unroll
            for (int c = 0; c < 2; c++)
                qf[g][c] = *(const bf16x8*)&qkv[qrow * 3072 + hh * 64 + c * 32 + quad * 8];
        }

        f32x4 o[2][4];
#pragma unroll
        for (int g = 0; g < 2; g++)
#pragma unroll
            for (int j = 0; j < 4; j++) o[g][j] = (f32x4){0.f, 0.f, 0.f, 0.f};
        float l_i[2][4] = {};

        {   // preload first tile (kt = unit)
            size_t kg = (rowbase + unit * 64) * 3072 + 1024 + hh * 64;
            short8 k0 = *(const short8*)&qkv[kg + (size_t)rr0 * 3072 + o8];
            short8 k1 = *(const short8*)&qkv[kg + (size_t)rr1 * 3072 + o8];
            short8 v0 = *(const short8*)&vtg[vbase + unit * 64 + (size_t)rr0 * L_ + o8];
            short8 v1 = *(const short8*)&vtg[vbase + unit * 64 + (size_t)rr1 * L_ + o8];
            *(short8*)&ks[0][rr0 * APAD + o8] = k0;
            *(short8*)&ks[0][rr1 * APAD + o8] = k1;
            *(short8*)&vt[rr0 * APAD + o8] = v0;
            *(short8*)&vt[rr1 * APAD + o8] = v1;
        }

        short8 kr0, kr1, vr0, vr1;
        for (int i = 0; i < cnt; i++) {
            const int kt = unit + 2 * i;
            const int p  = i & 1;
            __syncthreads();

            if (i + 1 < cnt) {                 // prefetch tile kt+2
                size_t kg = (rowbase + (kt + 2) * 64) * 3072 + 1024 + hh * 64;
                kr0 = *(const short8*)&qkv[kg + (size_t)rr0 * 3072 + o8];
                kr1 = *(const short8*)&qkv[kg + (size_t)rr1 * 3072 + o8];
                size_t vg = vbase + (kt + 2) * 64;
                vr0 = *(const short8*)&vtg[vg + (size_t)rr0 * L_ + o8];
                vr1 = *(const short8*)&vtg[vg + (size_t)rr1 * L_ + o8];
            }

            f32x4 s4[2][4];
#pragma unroll
            for (int g = 0; g < 2; g++)
#pragma unroll
                for (int j = 0; j < 4; j++) s4[g][j] = (f32x4){0.f, 0.f, 0.f, 0.f};
            __builtin_amdgcn_s_setprio(1);
#pragma unroll
            for (int c = 0; c < 2; c++)
#pragma unroll
                for (int j = 0; j < 4; j++) {
                    bf16x8 kf = *(const bf16x8*)&ks[p][(j * 16 + l16) * APAD + c * 32 + quad * 8];
#pragma unroll
                    for (int g = 0; g < 2; g++)
                        s4[g][j] = __builtin_amdgcn_mfma_f32_16x16x32_bf16(qf[g][c], kf, s4[g][j], 0, 0, 0);
                }
            __builtin_amdgcn_s_setprio(0);

            if (kt >= 2 * qq) {                // diagonal tile: causal mask
#pragma unroll
                for (int g = 0; g < 2; g++)
#pragma unroll
                    for (int j = 0; j < 4; j++) {
                        int lk = kt * 64 + j * 16 + l16;
#pragma unroll
                        for (int r = 0; r < 4; r++)
                            if (lk > qq * 128 + w * 32 + g * 16 + quad * 4 + r)
                                s4[g][j][r] = -INFINITY;
                    }
            }

#pragma unroll
            for (int g = 0; g < 2; g++)
#pragma unroll
                for (int r = 0; r < 4; r++) {
                    float p0 = __builtin_amdgcn_exp2f(s4[g][0][r]);
                    float p1 = __builtin_amdgcn_exp2f(s4[g][1][r]);
                    float p2 = __builtin_amdgcn_exp2f(s4[g][2][r]);
                    float p3 = __builtin_amdgcn_exp2f(s4[g][3][r]);
                    l_i[g][r] += (p0 + p1) + (p2 + p3);
                    uint2 pk = { pk_trunc(p0, p1), pk_trunc(p2, p3) };
                    *(uint2*)&ps[(w * 32 + g * 16 + quad * 4 + r) * APAD + 4 * l16] = pk;
                }

            __builtin_amdgcn_s_waitcnt(0xc07f);   // lgkmcnt(0): own-row P visible

            __builtin_amdgcn_s_setprio(1);
#pragma unroll
            for (int c = 0; c < 2; c++) {
                bf16x8 pf[2];
#pragma unroll
                for (int g = 0; g < 2; g++)
                    pf[g] = *(const bf16x8*)&ps[(w * 32 + g * 16 + l16) * APAD + c * 32 + quad * 8];
#pragma unroll
                for (int j = 0; j < 4; j++) {
                    bf16x8 vf = *(const bf16x8*)&vt[(j * 16 + l16) * APAD + c * 32 + quad * 8];
#pragma unroll
                    for (int g = 0; g < 2; g++)
                        o[g][j] = __builtin_amdgcn_mfma_f32_16x16x32_bf16(pf[g], vf, o[g][j], 0, 0, 0);
                }
            }
            __builtin_amdgcn_s_setprio(0);

            __syncthreads();
            if (i + 1 < cnt) {
                *(short8*)&ks[p ^ 1][rr0 * APAD + o8] = kr0;
                *(short8*)&ks[p ^ 1][rr1 * APAD + o8] = kr1;
                *(short8*)&vt[rr0 * APAD + o8] = vr0;
                *(short8*)&vt[rr1 * APAD + o8] = vr1;
            }
        }

        // phase epilogue: store unnormalized bf16 partials + l sums
#pragma unroll
        for (int g = 0; g < 2; g++)
#pragma unroll
            for (int r = 0; r < 4; r++) {
                float l = l_i[g][r];
                l += __shfl_xor(l, 1);
                l += __shfl_xor(l, 2);
                l += __shfl_xor(l, 4);
                l += __shfl_xor(l, 8);
                int rowq = qq * 128 + w * 32 + g * 16 + quad * 4 + r;
                size_t grow = (size_t)(b * H_ + hh) * L_ + rowq;
                if (l16 == 0) lP[grow] = l;
#pragma unroll
                for (int j = 0; j < 4; j++)
                    oP[grow * 64 + j * 16 + l16] = f2bf(o[g][j][r]);
            }
    }
}

// ---------------------------------------------------------------------------
// Combine the two attention split-K partials: zb = (oA+oB)/(lA+lB), bf16.
// ---------------------------------------------------------------------------
__global__ __launch_bounds__(256) void attn_combine(const unsigned short* __restrict__ oA,
                                                    const unsigned short* __restrict__ oB,
                                                    const float* __restrict__ lA,
                                                    const float* __restrict__ lB,
                                                    unsigned short* __restrict__ zb) {
    const int t = threadIdx.x;
    const size_t idx4 = ((size_t)blockIdx.x * 256 + t) * 4;
    const size_t row  = idx4 >> 6;          // 0 .. B*H*L-1
    const int    col  = (int)(idx4 & 63);

    float inv = 1.f / (lA[row] + lB[row]);
    ushort4 ua = *(const ushort4*)&oA[idx4];
    ushort4 ub = *(const ushort4*)&oB[idx4];

    const int bq   = (int)(row >> 15);          // batch
    const int hh   = (int)((row >> 11) & 15);   // head
    const int rowq = (int)(row & 2047);
    size_t z = ((size_t)(bq * L_ + rowq)) * 1024 + hh * 64 + col;
    ushort4 pk = { f2bf((bf2f(ua.x) + bf2f(ub.x)) * inv),
                   f2bf((bf2f(ua.y) + bf2f(ub.y)) * inv),
                   f2bf((bf2f(ua.z) + bf2f(ub.z)) * inv),
                   f2bf((bf2f(ua.w) + bf2f(ub.w)) * inv) };
    *(ushort4*)&zb[z] = pk;
}

// ---------------------------------------------------------------------------
// LayerNorm(a + sum of 4 bf16 partial planes + bias) * g + beta.
// ---------------------------------------------------------------------------
template <int WRITE_BF16>
__global__ __launch_bounds__(256) void ln5_kernel(const float* __restrict__ a,
                                                  const unsigned short* __restrict__ q0,
                                                  const unsigned short* __restrict__ q1,
                                                  const unsigned short* __restrict__ q2,
                                                  const unsigned short* __restrict__ q3,
                                                  const float* __restrict__ bias,
                                                  const float* __restrict__ g,
                                                  const float* __restrict__ be,
                                                  float* __restrict__ out,
                                                  unsigned short* __restrict__ out_bf) {
    __shared__ float s1[256], s2[256];
    const int row = blockIdx.x;
    const int t   = threadIdx.x;
    const size_t base = (size_t)row * E_ + t * 4;

    float4 ya = *(const float4*)&a[base];
    ushort4 u0 = *(const ushort4*)&q0[base];
    ushort4 u1 = *(const ushort4*)&q1[base];
    ushort4 u2 = *(const ushort4*)&q2[base];
    ushort4 u3 = *(const ushort4*)&q3[base];
    float4 bb = *(const float4*)&bias[t * 4];
    float y0 = ya.x + bb.x + bf2f(u0.x) + bf2f(u1.x) + bf2f(u2.x) + bf2f(u3.x);
    float y1 = ya.y + bb.y + bf2f(u0.y) + bf2f(u1.y) + bf2f(u2.y) + bf2f(u3.y);
    float y2 = ya.z + bb.z + bf2f(u0.z) + bf2f(u1.z) + bf2f(u2.z) + bf2f(u3.z);
    float y3 = ya.w + bb.w + bf2f(u0.w) + bf2f(u1.w) + bf2f(u2.w) + bf2f(u3.w);

    s1[t] = y0 + y1 + y2 + y3;
    s2[t] = y0 * y0 + y1 * y1 + y2 * y2 + y3 * y3;
    __syncthreads();
    for (int off = 128; off > 0; off >>= 1) {
        if (t < off) { s1[t] += s1[t + off]; s2[t] += s2[t + off]; }
        __syncthreads();
    }
    float mean = s1[0] * (1.0f / E_);
    float var  = s2[0] * (1.0f / E_) - mean * mean;
    float rstd = rsqrtf(var + 1e-5f);

    float4 gv = *(const float4*)&g[t * 4];
    float4 bv = *(const float4*)&be[t * 4];
    float4 ov;
    ov.x = (y0 - mean) * rstd * gv.x + bv.x;
    ov.y = (y1 - mean) * rstd * gv.y + bv.y;
    ov.z = (y2 - mean) * rstd * gv.z + bv.z;
    ov.w = (y3 - mean) * rstd * gv.w + bv.w;
    *(float4*)&out[base] = ov;
    if (WRITE_BF16) {
        ushort4 pk = { f2bf(ov.x), f2bf(ov.y), f2bf(ov.z), f2bf(ov.w) };
        *(ushort4*)&out_bf[base] = pk;
    }
}

// ---------------------------------------------------------------------------
extern "C" void kernel_launch(void* const* d_in, const int* in_sizes, int n_in,
                              void* d_out, int out_size, void* d_ws, size_t ws_size,
                              hipStream_t stream)
{
    const float* x     = (const float*)d_in[0];
    const float* Wq    = (const float*)d_in[2];
    const float* bq    = (const float*)d_in[3];
    const float* Wk    = (const float*)d_in[4];
    const float* bk    = (const float*)d_in[5];
    const float* Wv    = (const float*)d_in[6];
    const float* bv    = (const float*)d_in[7];
    const float* Wo    = (const float*)d_in[8];
    const float* bo    = (const float*)d_in[9];
    const float* W1    = (const float*)d_in[10];
    const float* c1    = (const float*)d_in[11];
    const float* W2    = (const float*)d_in[12];
    const float* c2    = (const float*)d_in[13];
    const float* g1    = (const float*)d_in[14];
    const float* beta1 = (const float*)d_in[15];
    const float* g2    = (const float*)d_in[16];
    const float* beta2 = (const float*)d_in[17];
    float* out = (float*)d_out;

    const size_t MB = 1024 * 1024;
    char* w = (char*)d_ws;
    unsigned short* xb    = (unsigned short*)(w + 0 * MB);    // [0,8)   prep..QKV
    unsigned short* Wqkvt = (unsigned short*)(w + 8 * MB);    // [8,14)
    unsigned short* Wot   = (unsigned short*)(w + 14 * MB);   // [14,16)
    unsigned short* W1t   = (unsigned short*)(w + 16 * MB);   // [16,24)
    unsigned short* W2t   = (unsigned short*)(w + 24 * MB);   // [24,32)
    float*          bqkv  = (float*)(w + 32 * MB);            // [32,33)  prep..QKV
    unsigned short* qkv   = (unsigned short*)(w + 33 * MB);   // [33,57)  QKV..attn
    float*          h     = (float*)(w + 65 * MB);            // [65,81)  LN1..LN2
    unsigned short* vtg   = (unsigned short*)(w + 89 * MB);   // [89,97)  vT..attn
    // attention split-K partials (attn..combine window), bf16 now:
    unsigned short* oPA   = (unsigned short*)(w + 57 * MB);   // [57,65)
    unsigned short* oPB   = (unsigned short*)(w + 81 * MB);   // [81,89)
    float*          lPA   = (float*)(w + 32 * MB);            // over dead bqkv
    float*          lPB   = (float*)(w + 32 * MB + 262144);
    unsigned short* zb    = (unsigned short*)(w + 0 * MB);    // combine..Wo (over dead xb)
    // Wo partials (bf16, 8 MB each): over dead qkv + dead vtg
    unsigned short* ap0   = (unsigned short*)(w + 33 * MB);
    unsigned short* ap1   = (unsigned short*)(w + 41 * MB);
    unsigned short* ap2   = (unsigned short*)(w + 49 * MB);
    unsigned short* ap3   = (unsigned short*)(w + 89 * MB);
    unsigned short* hb    = (unsigned short*)(w + 0 * MB);    // LN1..FFN1 (over zb, dead by then)
    unsigned short* ff1b  = (unsigned short*)(w + 33 * MB);   // FFN1..FFN2 [33,65)
    // FFN2 partials (bf16): over dead hb/Wqkvt/Wot/W1t + tail
    unsigned short* fp0   = (unsigned short*)(w + 0 * MB);
    unsigned short* fp1   = (unsigned short*)(w + 8 * MB);
    unsigned short* fp2   = (unsigned short*)(w + 16 * MB);
    unsigned short* fp3   = (unsigned short*)(w + 81 * MB);

    static bool lds_inited = false;
    if (!lds_inited) {
        (void)hipFuncSetAttribute((const void*)&gemm256<0, 0>,
                                  hipFuncAttributeMaxDynamicSharedMemorySize, 131072);
        (void)hipFuncSetAttribute((const void*)&gemm256<1, 0>,
                                  hipFuncAttributeMaxDynamicSharedMemorySize, 131072);
        (void)hipFuncSetAttribute((const void*)&gemm256<0, 1>,
                                  hipFuncAttributeMaxDynamicSharedMemorySize, 131072);
        lds_inited = true;
    }

    dim3 blk(256);
    dim3 blk2(512);

    prep<<<dim3(16396), blk, 0, stream>>>(x, Wq, Wk, Wv, bq, bk, bv, Wo, W1, W2,
                                          xb, Wqkvt, Wot, W1t, W2t, bqkv);

    // QKV: M=4096, N=3072 -> 16x12 tiles = 192 blocks
    gemm256<0, 0><<<dim3(192), blk2, 131072, stream>>>(xb, Wqkvt, bqkv,
                                                       qkv, nullptr, nullptr, nullptr,
                                                       M_, 3072, E_);

    v_transpose_perm<<<dim3(L_ / 64, H_, B_), blk, 0, stream>>>(qkv, vtg);

    // attn v8b: split-K pairs, grid 512 (2 blocks/CU), 17 tiles each
    attn_mfma<<<dim3(512), blk, 0, stream>>>(qkv, vtg, oPA, oPB, lPA, lPB);

    // combine: B*H*L*64 elems, 4/thread -> 4096 blocks
    attn_combine<<<dim3(4096), blk, 0, stream>>>(oPA, oPB, lPA, lPB, zb);

    // Wo: N=1024 -> 4 n-tiles, split-K=4 -> 256 blocks (KT=4 per plane)
    gemm256<0, 1><<<dim3(256), blk2, 131072, stream>>>(zb, Wot, nullptr,
                                                       ap0, ap1, ap2, ap3,
                                                       M_, E_, E_);

    ln5_kernel<1><<<dim3(M_), blk, 0, stream>>>(x, ap0, ap1, ap2, ap3, bo, g1, beta1, h, hb);

    // FFN1: M=4096, N=4096 -> 16x16 = 256 blocks
    gemm256<1, 0><<<dim3(256), blk2, 131072, stream>>>(hb, W1t, c1,
                                                       ff1b, nullptr, nullptr, nullptr,
                                                       M_, DFF, E_);

    // FFN2: N=1024 -> 4 n-tiles, split-K=4 -> 256 blocks (KT=16 per plane)
    gemm256<0, 1><<<dim3(256), blk2, 131072, stream>>>(ff1b, W2t, nullptr,
                                                       fp0, fp1, fp2, fp3,
                                                       M_, E_, DFF);

    ln5_kernel<0><<<dim3(M_), blk, 0, stream>>>(h, fp0, fp1, fp2, fp3, c2, g2, beta2, out, nullptr);
}